// Round 1
// baseline (1298.677 us; speedup 1.0000x reference)
//
#include <hip/hip_runtime.h>
#include <math.h>

#define N 4096
#define D 128
#define H 512
#define INV_T 5.0f

// ---------------------------------------------------------------------------
// GEMM: C = A(MxK) @ B(NnxK)^T + bias ; resid=1: C = A + relu(...)  (needs K==Nn)
// 64x64 tile, BK=16, 256 threads, 4x4 micro-tile per thread.
// ---------------------------------------------------------------------------
__global__ __launch_bounds__(256) void gemm_abt(const float* __restrict__ A,
    const float* __restrict__ B, const float* __restrict__ bias,
    float* __restrict__ C, int M, int Nn, int K, int resid)
{
    __shared__ float As[64][17];
    __shared__ float Bs[64][17];
    const int t = threadIdx.x;
    const int bm = blockIdx.y * 64, bn = blockIdx.x * 64;
    const int tx = t & 15, ty = t >> 4;
    const int lrow = t >> 2, lkq = (t & 3) << 2;
    float acc[4][4] = {};

    for (int k0 = 0; k0 < K; k0 += 16) {
        float4 av = *(const float4*)(A + (size_t)(bm + lrow) * K + k0 + lkq);
        float4 bv = *(const float4*)(B + (size_t)(bn + lrow) * K + k0 + lkq);
        As[lrow][lkq + 0] = av.x; As[lrow][lkq + 1] = av.y;
        As[lrow][lkq + 2] = av.z; As[lrow][lkq + 3] = av.w;
        Bs[lrow][lkq + 0] = bv.x; Bs[lrow][lkq + 1] = bv.y;
        Bs[lrow][lkq + 2] = bv.z; Bs[lrow][lkq + 3] = bv.w;
        __syncthreads();
        #pragma unroll
        for (int k = 0; k < 16; ++k) {
            float a0 = As[ty * 4 + 0][k], a1 = As[ty * 4 + 1][k];
            float a2 = As[ty * 4 + 2][k], a3 = As[ty * 4 + 3][k];
            float b0 = Bs[tx * 4 + 0][k], b1 = Bs[tx * 4 + 1][k];
            float b2 = Bs[tx * 4 + 2][k], b3 = Bs[tx * 4 + 3][k];
            acc[0][0] = fmaf(a0, b0, acc[0][0]); acc[0][1] = fmaf(a0, b1, acc[0][1]);
            acc[0][2] = fmaf(a0, b2, acc[0][2]); acc[0][3] = fmaf(a0, b3, acc[0][3]);
            acc[1][0] = fmaf(a1, b0, acc[1][0]); acc[1][1] = fmaf(a1, b1, acc[1][1]);
            acc[1][2] = fmaf(a1, b2, acc[1][2]); acc[1][3] = fmaf(a1, b3, acc[1][3]);
            acc[2][0] = fmaf(a2, b0, acc[2][0]); acc[2][1] = fmaf(a2, b1, acc[2][1]);
            acc[2][2] = fmaf(a2, b2, acc[2][2]); acc[2][3] = fmaf(a2, b3, acc[2][3]);
            acc[3][0] = fmaf(a3, b0, acc[3][0]); acc[3][1] = fmaf(a3, b1, acc[3][1]);
            acc[3][2] = fmaf(a3, b2, acc[3][2]); acc[3][3] = fmaf(a3, b3, acc[3][3]);
        }
        __syncthreads();
    }
    #pragma unroll
    for (int i2 = 0; i2 < 4; ++i2) {
        int m = bm + ty * 4 + i2;
        #pragma unroll
        for (int j2 = 0; j2 < 4; ++j2) {
            int n = bn + tx * 4 + j2;
            float v = acc[i2][j2] + bias[n];
            if (resid) v = A[(size_t)m * K + n] + fmaxf(v, 0.0f);
            C[(size_t)m * Nn + n] = v;
        }
    }
}

// ---------------------------------------------------------------------------
// Distance: Out[i][j] = -||X_i - Y_j|| / T  (direct differences, no cancellation)
// self=1: diagonal = -(0 + 1e6)/T = -5e6
// ---------------------------------------------------------------------------
__global__ __launch_bounds__(256) void dist_kernel(const float* __restrict__ X,
    const float* __restrict__ Y, float* __restrict__ Out, int self)
{
    __shared__ float Xs[32][132];  // 132: float4-aligned pad, 4-way bank alias (cheap)
    __shared__ float Ys[32][132];
    const int t = threadIdx.x;
    const int bi = blockIdx.y << 5, bj = blockIdx.x << 5;
    #pragma unroll
    for (int q = 0; q < 4; ++q) {
        int idx = t + q * 256;       // 0..1023 float4 slots (32 rows x 32 quads)
        int row = idx >> 5;
        int col = (idx & 31) << 2;
        *(float4*)&Xs[row][col] = *(const float4*)(X + (size_t)(bi + row) * D + col);
        *(float4*)&Ys[row][col] = *(const float4*)(Y + (size_t)(bj + row) * D + col);
    }
    __syncthreads();
    const int j = t & 31, i0 = t >> 5;
    float d2[4] = {0.f, 0.f, 0.f, 0.f};
    #pragma unroll 4
    for (int k = 0; k < D; ++k) {
        float yv = Ys[j][k];
        #pragma unroll
        for (int r = 0; r < 4; ++r) {
            float diff = Xs[i0 + (r << 3)][k] - yv;
            d2[r] = fmaf(diff, diff, d2[r]);
        }
    }
    #pragma unroll
    for (int r = 0; r < 4; ++r) {
        int i = bi + i0 + (r << 3);
        int jj = bj + j;
        float a = -sqrtf(d2[r]) * INV_T;
        if (self && i == jj) a = -5.0e6f;
        Out[(size_t)i * N + jj] = a;
    }
}

// ---------------------------------------------------------------------------
// Row stats over concatenated [Apos_row, Aneg_row] (8192 entries): max + sum-exp
// ---------------------------------------------------------------------------
__global__ __launch_bounds__(256) void row_stats(const float* __restrict__ Apos,
    const float* __restrict__ Aneg, float* __restrict__ m_row, float* __restrict__ s_row)
{
    const int i = blockIdx.x;
    const int t = threadIdx.x;
    __shared__ float red[256];
    const float* rp = Apos + (size_t)i * N;
    const float* rn = Aneg + (size_t)i * N;
    float m = -3.0e38f;
    for (int j = t; j < N; j += 256) {
        m = fmaxf(m, rp[j]);
        m = fmaxf(m, rn[j]);
    }
    red[t] = m; __syncthreads();
    for (int s = 128; s > 0; s >>= 1) {
        if (t < s) red[t] = fmaxf(red[t], red[t + s]);
        __syncthreads();
    }
    m = red[0]; __syncthreads();
    float sum = 0.f;
    for (int j = t; j < N; j += 256) {
        sum += expf(rp[j] - m) + expf(rn[j] - m);
    }
    red[t] = sum; __syncthreads();
    for (int s = 128; s > 0; s >>= 1) {
        if (t < s) red[t] += red[t + s];
        __syncthreads();
    }
    if (t == 0) { m_row[i] = m; s_row[i] = red[0]; }
}

// ---------------------------------------------------------------------------
// Column stats: online (max,sum) partials over 256-row chunks, then combine.
// ---------------------------------------------------------------------------
__global__ __launch_bounds__(256) void col_stats_partial(const float* __restrict__ Apos,
    const float* __restrict__ Aneg, float* __restrict__ part_m, float* __restrict__ part_s)
{
    const int col = blockIdx.x * 256 + threadIdx.x;  // 0..4095
    const int chunk = blockIdx.y;                    // 0..15
    const int mat = blockIdx.z;                      // 0: pos, 1: neg
    const float* Asrc = mat ? Aneg : Apos;
    const int r0 = chunk * 256;
    float m = -3.0e38f, s = 0.f;
    #pragma unroll 4
    for (int r = 0; r < 256; ++r) {
        float a = Asrc[(size_t)(r0 + r) * N + col];
        float mn = fmaxf(m, a);
        s = s * expf(m - mn) + expf(a - mn);
        m = mn;
    }
    const size_t o = ((size_t)(mat * 16 + chunk)) * N + col;
    part_m[o] = m;
    part_s[o] = s;
}

__global__ __launch_bounds__(256) void col_stats_combine(const float* __restrict__ part_m,
    const float* __restrict__ part_s, float* __restrict__ m_col, float* __restrict__ isc)
{
    const int jg = blockIdx.x * 256 + threadIdx.x;   // 0..8191
    const int mat = jg >> 12;
    const int col = jg & (N - 1);
    float m = -3.0e38f;
    #pragma unroll
    for (int c = 0; c < 16; ++c)
        m = fmaxf(m, part_m[((size_t)(mat * 16 + c)) * N + col]);
    float s = 0.f;
    #pragma unroll
    for (int c = 0; c < 16; ++c) {
        size_t o = ((size_t)(mat * 16 + c)) * N + col;
        s += part_s[o] * expf(part_m[o] - m);
    }
    m_col[jg] = m;
    isc[jg] = 1.0f / sqrtf(s);
}

// ---------------------------------------------------------------------------
// Final fused: per row i, build P_pos/P_neg on the fly, accumulate
// u = P_pos @ y_pos, w = P_neg @ x, s_pos, s_neg; V = sn*u - sp*sn*w; sum V^2.
// ---------------------------------------------------------------------------
__global__ __launch_bounds__(256) void final_kernel(const float* __restrict__ Apos,
    const float* __restrict__ Aneg, const float* __restrict__ y_pos,
    const float* __restrict__ x, const float* __restrict__ m_row,
    const float* __restrict__ s_row, const float* __restrict__ m_col,
    const float* __restrict__ isc, double* __restrict__ acc)
{
    const int i = blockIdx.x;
    const int t = threadIdx.x;
    __shared__ float Pp[256], Pn[256];
    __shared__ float red[256];
    __shared__ float uw[256];
    const float mr = m_row[i];
    const float isr = 1.0f / sqrtf(s_row[i]);
    const size_t rowoff = (size_t)i * N;
    float uacc = 0.f, sp = 0.f, sn = 0.f;

    for (int c = 0; c < N; c += 256) {
        int j = c + t;
        float ap = Apos[rowoff + j];
        float an = Aneg[rowoff + j];
        float pp = expf(ap - 0.5f * (mr + m_col[j])) * (isr * isc[j]);
        float pn = expf(an - 0.5f * (mr + m_col[N + j])) * (isr * isc[N + j]);
        sp += pp; sn += pn;
        __syncthreads();          // protect prior iteration's reads of Pp/Pn
        Pp[t] = pp; Pn[t] = pn;
        __syncthreads();
        if (t < 128) {
            const float* yp = y_pos + (size_t)c * D + t;
            #pragma unroll 8
            for (int jj = 0; jj < 256; ++jj)
                uacc = fmaf(Pp[jj], yp[(size_t)jj * D], uacc);
        } else {
            const float* xp = x + (size_t)c * D + (t - 128);
            #pragma unroll 8
            for (int jj = 0; jj < 256; ++jj)
                uacc = fmaf(Pn[jj], xp[(size_t)jj * D], uacc);
        }
    }
    // reduce s_pos, s_neg over block
    red[t] = sp; __syncthreads();
    for (int s = 128; s > 0; s >>= 1) { if (t < s) red[t] += red[t + s]; __syncthreads(); }
    float SP = red[0]; __syncthreads();
    red[t] = sn; __syncthreads();
    for (int s = 128; s > 0; s >>= 1) { if (t < s) red[t] += red[t + s]; __syncthreads(); }
    float SN = red[0]; __syncthreads();

    uw[t] = uacc; __syncthreads();
    float vsq = 0.f;
    if (t < 128) {
        float v = SN * uw[t] - SP * SN * uw[128 + t];
        vsq = v * v;
    }
    red[t] = vsq; __syncthreads();
    for (int s = 128; s > 0; s >>= 1) { if (t < s) red[t] += red[t + s]; __syncthreads(); }
    if (t == 0) atomicAdd(acc, (double)red[0]);
}

__global__ void init_acc(double* acc) { *acc = 0.0; }

__global__ void finalize(const double* __restrict__ acc, float* __restrict__ out)
{
    out[0] = (float)(*acc * (1.0 / ((double)N * (double)D)));
}

// ---------------------------------------------------------------------------
extern "C" void kernel_launch(void* const* d_in, const int* in_sizes, int n_in,
                              void* d_out, int out_size, void* d_ws, size_t ws_size,
                              hipStream_t stream)
{
    const float* y_pos = (const float*)d_in[0];
    const float* eps   = (const float*)d_in[1];
    const float* W_in  = (const float*)d_in[2];
    const float* b_in  = (const float*)d_in[3];
    const float* W_blk = (const float*)d_in[4];
    const float* b_blk = (const float*)d_in[5];
    const float* W_out = (const float*)d_in[6];
    const float* b_out = (const float*)d_in[7];
    float* out = (float*)d_out;
    (void)in_sizes; (void)n_in; (void)out_size; (void)ws_size;

    double* acc = (double*)d_ws;
    float* base = (float*)d_ws + 4;
    float* x0     = base; base += (size_t)N * H;
    float* x1     = base; base += (size_t)N * H;
    float* xo     = base; base += (size_t)N * D;
    float* Apos   = base; base += (size_t)N * N;
    float* Aneg   = base; base += (size_t)N * N;
    float* m_row  = base; base += N;
    float* s_row  = base; base += N;
    float* m_col  = base; base += 2 * N;
    float* isc    = base; base += 2 * N;
    float* part_m = base; base += 32 * N;
    float* part_s = base; base += 32 * N;

    // --- generator ---
    dim3 gh(H / 64, N / 64);
    gemm_abt<<<gh, 256, 0, stream>>>(eps, W_in, b_in, x0, N, H, D, 0);
    gemm_abt<<<gh, 256, 0, stream>>>(x0, W_blk + 0 * H * H, b_blk + 0 * H, x1, N, H, H, 1);
    gemm_abt<<<gh, 256, 0, stream>>>(x1, W_blk + 1 * H * H, b_blk + 1 * H, x0, N, H, H, 1);
    gemm_abt<<<gh, 256, 0, stream>>>(x0, W_blk + 2 * H * H, b_blk + 2 * H, x1, N, H, H, 1);
    gemm_abt<<<gh, 256, 0, stream>>>(x1, W_blk + 3 * H * H, b_blk + 3 * H, x0, N, H, H, 1);
    gemm_abt<<<dim3(D / 64, N / 64), 256, 0, stream>>>(x0, W_out, b_out, xo, N, D, H, 0);

    // --- distance matrices (store a = -d/T) ---
    dim3 gd(N / 32, N / 32);
    dist_kernel<<<gd, 256, 0, stream>>>(xo, y_pos, Apos, 0);
    dist_kernel<<<gd, 256, 0, stream>>>(xo, xo, Aneg, 1);

    // --- softmax stats ---
    row_stats<<<N, 256, 0, stream>>>(Apos, Aneg, m_row, s_row);
    col_stats_partial<<<dim3(16, 16, 2), 256, 0, stream>>>(Apos, Aneg, part_m, part_s);
    col_stats_combine<<<32, 256, 0, stream>>>(part_m, part_s, m_col, isc);

    // --- fused final reduction ---
    init_acc<<<1, 1, 0, stream>>>(acc);
    final_kernel<<<N, 256, 0, stream>>>(Apos, Aneg, y_pos, xo, m_row, s_row, m_col, isc, acc);
    finalize<<<1, 1, 0, stream>>>(acc, out);
}

// Round 2
// 623.140 us; speedup vs baseline: 2.0841x; 2.0841x over previous
//
#include <hip/hip_runtime.h>
#include <math.h>

#define N 4096
#define D 128
#define H 512
#define INV_T 5.0f
#define KSPLIT 8

// ---------------------------------------------------------------------------
// GEMM: C = A(MxK) @ B(NnxK)^T + bias ; resid=1: C = A + relu(...) (needs K==Nn)
// 64x64 tile, BK=16, 256 threads, 4x4 micro-tile. LDS stored transposed [k][m]
// (pad 68 => 16B-aligned rows) so fragments are ds_read_b128.
// ---------------------------------------------------------------------------
__global__ __launch_bounds__(256) void gemm_abt(const float* __restrict__ A,
    const float* __restrict__ B, const float* __restrict__ bias,
    float* __restrict__ C, int M, int Nn, int K, int resid)
{
    __shared__ float As[16][68];
    __shared__ float Bs[16][68];
    const int t = threadIdx.x;
    const int bm = blockIdx.y * 64, bn = blockIdx.x * 64;
    const int tx = t & 15, ty = t >> 4;
    const int lrow = t >> 2, lkq = (t & 3) << 2;
    float acc[4][4] = {};

    for (int k0 = 0; k0 < K; k0 += 16) {
        float4 av = *(const float4*)(A + (size_t)(bm + lrow) * K + k0 + lkq);
        float4 bv = *(const float4*)(B + (size_t)(bn + lrow) * K + k0 + lkq);
        __syncthreads();   // protect previous iteration's reads
        As[lkq + 0][lrow] = av.x; As[lkq + 1][lrow] = av.y;
        As[lkq + 2][lrow] = av.z; As[lkq + 3][lrow] = av.w;
        Bs[lkq + 0][lrow] = bv.x; Bs[lkq + 1][lrow] = bv.y;
        Bs[lkq + 2][lrow] = bv.z; Bs[lkq + 3][lrow] = bv.w;
        __syncthreads();
        #pragma unroll
        for (int k = 0; k < 16; ++k) {
            float4 a = *(const float4*)&As[k][ty * 4];
            float4 b = *(const float4*)&Bs[k][tx * 4];
            acc[0][0] = fmaf(a.x, b.x, acc[0][0]); acc[0][1] = fmaf(a.x, b.y, acc[0][1]);
            acc[0][2] = fmaf(a.x, b.z, acc[0][2]); acc[0][3] = fmaf(a.x, b.w, acc[0][3]);
            acc[1][0] = fmaf(a.y, b.x, acc[1][0]); acc[1][1] = fmaf(a.y, b.y, acc[1][1]);
            acc[1][2] = fmaf(a.y, b.z, acc[1][2]); acc[1][3] = fmaf(a.y, b.w, acc[1][3]);
            acc[2][0] = fmaf(a.z, b.x, acc[2][0]); acc[2][1] = fmaf(a.z, b.y, acc[2][1]);
            acc[2][2] = fmaf(a.z, b.z, acc[2][2]); acc[2][3] = fmaf(a.z, b.w, acc[2][3]);
            acc[3][0] = fmaf(a.w, b.x, acc[3][0]); acc[3][1] = fmaf(a.w, b.y, acc[3][1]);
            acc[3][2] = fmaf(a.w, b.z, acc[3][2]); acc[3][3] = fmaf(a.w, b.w, acc[3][3]);
        }
    }
    #pragma unroll
    for (int i2 = 0; i2 < 4; ++i2) {
        int m = bm + ty * 4 + i2;
        #pragma unroll
        for (int j2 = 0; j2 < 4; ++j2) {
            int n = bn + tx * 4 + j2;
            float v = acc[i2][j2] + bias[n];
            if (resid) v = A[(size_t)m * K + n] + fmaxf(v, 0.0f);
            C[(size_t)m * Nn + n] = v;
        }
    }
}

// ---------------------------------------------------------------------------
// Row squared norms of X (gen output) and Y (y_pos). grid (N,2), block 128.
// ---------------------------------------------------------------------------
__global__ void row_norms(const float* __restrict__ X, const float* __restrict__ Y,
                          float* __restrict__ nx, float* __restrict__ ny)
{
    __shared__ float red[128];
    const float* src = blockIdx.y ? Y : X;
    float* dst = blockIdx.y ? ny : nx;
    const int t = threadIdx.x;
    float v = src[(size_t)blockIdx.x * D + t];
    red[t] = v * v; __syncthreads();
    for (int s = 64; s > 0; s >>= 1) { if (t < s) red[t] += red[t + s]; __syncthreads(); }
    if (!t) dst[blockIdx.x] = red[0];
}

// ---------------------------------------------------------------------------
// Distance as GEMM: a = -INV_T * sqrt(max(nx[i]+ny[j]-2*dot,0)); diag -> -5e6
// ---------------------------------------------------------------------------
__global__ __launch_bounds__(256) void dist_gemm(const float* __restrict__ X,
    const float* __restrict__ Y, const float* __restrict__ nx,
    const float* __restrict__ ny, float* __restrict__ Out, int self)
{
    __shared__ float Xs[16][68];
    __shared__ float Ysh[16][68];
    const int t = threadIdx.x;
    const int bm = blockIdx.y * 64, bn = blockIdx.x * 64;
    const int tx = t & 15, ty = t >> 4;
    const int lrow = t >> 2, lkq = (t & 3) << 2;
    float acc[4][4] = {};

    for (int k0 = 0; k0 < D; k0 += 16) {
        float4 av = *(const float4*)(X + (size_t)(bm + lrow) * D + k0 + lkq);
        float4 bv = *(const float4*)(Y + (size_t)(bn + lrow) * D + k0 + lkq);
        __syncthreads();
        Xs[lkq + 0][lrow] = av.x; Xs[lkq + 1][lrow] = av.y;
        Xs[lkq + 2][lrow] = av.z; Xs[lkq + 3][lrow] = av.w;
        Ysh[lkq + 0][lrow] = bv.x; Ysh[lkq + 1][lrow] = bv.y;
        Ysh[lkq + 2][lrow] = bv.z; Ysh[lkq + 3][lrow] = bv.w;
        __syncthreads();
        #pragma unroll
        for (int k = 0; k < 16; ++k) {
            float4 a = *(const float4*)&Xs[k][ty * 4];
            float4 b = *(const float4*)&Ysh[k][tx * 4];
            acc[0][0] = fmaf(a.x, b.x, acc[0][0]); acc[0][1] = fmaf(a.x, b.y, acc[0][1]);
            acc[0][2] = fmaf(a.x, b.z, acc[0][2]); acc[0][3] = fmaf(a.x, b.w, acc[0][3]);
            acc[1][0] = fmaf(a.y, b.x, acc[1][0]); acc[1][1] = fmaf(a.y, b.y, acc[1][1]);
            acc[1][2] = fmaf(a.y, b.z, acc[1][2]); acc[1][3] = fmaf(a.y, b.w, acc[1][3]);
            acc[2][0] = fmaf(a.z, b.x, acc[2][0]); acc[2][1] = fmaf(a.z, b.y, acc[2][1]);
            acc[2][2] = fmaf(a.z, b.z, acc[2][2]); acc[2][3] = fmaf(a.z, b.w, acc[2][3]);
            acc[3][0] = fmaf(a.w, b.x, acc[3][0]); acc[3][1] = fmaf(a.w, b.y, acc[3][1]);
            acc[3][2] = fmaf(a.w, b.z, acc[3][2]); acc[3][3] = fmaf(a.w, b.w, acc[3][3]);
        }
    }
    #pragma unroll
    for (int i2 = 0; i2 < 4; ++i2) {
        int m = bm + ty * 4 + i2;
        float nxm = nx[m];
        #pragma unroll
        for (int j2 = 0; j2 < 4; ++j2) {
            int n = bn + tx * 4 + j2;
            float d2 = nxm + ny[n] - 2.0f * acc[i2][j2];
            d2 = fmaxf(d2, 0.0f);
            float a = -sqrtf(d2) * INV_T;
            if (self && (m == n)) a = -5.0e6f;
            Out[(size_t)m * N + n] = a;
        }
    }
}

// ---------------------------------------------------------------------------
// Online row stats over concatenated [Apos_row, Aneg_row]: (max, sum-exp)
// ---------------------------------------------------------------------------
__global__ __launch_bounds__(256) void row_stats(const float* __restrict__ Apos,
    const float* __restrict__ Aneg, float* __restrict__ m_row, float* __restrict__ s_row)
{
    const int i = blockIdx.x, t = threadIdx.x;
    __shared__ float rm[256], rs[256];
    const float* rp = Apos + (size_t)i * N;
    const float* rn = Aneg + (size_t)i * N;
    float m = -3.0e38f, s = 0.f;
    for (int j = t; j < N; j += 256) {
        float a = rp[j];
        float mn = fmaxf(m, a); s = s * __expf(m - mn) + __expf(a - mn); m = mn;
        a = rn[j];
        mn = fmaxf(m, a); s = s * __expf(m - mn) + __expf(a - mn); m = mn;
    }
    rm[t] = m; rs[t] = s; __syncthreads();
    for (int st = 128; st > 0; st >>= 1) {
        if (t < st) {
            float m2 = rm[t + st], s2 = rs[t + st];
            float mn = fmaxf(rm[t], m2);
            rs[t] = rs[t] * __expf(rm[t] - mn) + s2 * __expf(m2 - mn);
            rm[t] = mn;
        }
        __syncthreads();
    }
    if (!t) { m_row[i] = rm[0]; s_row[i] = rs[0]; }
}

// ---------------------------------------------------------------------------
// Column stats: online partials over 256-row chunks, then combine.
// ---------------------------------------------------------------------------
__global__ __launch_bounds__(256) void col_stats_partial(const float* __restrict__ Apos,
    const float* __restrict__ Aneg, float* __restrict__ part_m, float* __restrict__ part_s)
{
    const int col = blockIdx.x * 256 + threadIdx.x;
    const int chunk = blockIdx.y;
    const int mat = blockIdx.z;
    const float* Asrc = mat ? Aneg : Apos;
    const int r0 = chunk * 256;
    float m = -3.0e38f, s = 0.f;
    #pragma unroll 4
    for (int r = 0; r < 256; ++r) {
        float a = Asrc[(size_t)(r0 + r) * N + col];
        float mn = fmaxf(m, a);
        s = s * __expf(m - mn) + __expf(a - mn);
        m = mn;
    }
    const size_t o = ((size_t)(mat * 16 + chunk)) * N + col;
    part_m[o] = m;
    part_s[o] = s;
}

__global__ __launch_bounds__(256) void col_stats_combine(const float* __restrict__ part_m,
    const float* __restrict__ part_s, float* __restrict__ m_col, float* __restrict__ isc)
{
    const int jg = blockIdx.x * 256 + threadIdx.x;
    const int mat = jg >> 12;
    const int col = jg & (N - 1);
    float m = -3.0e38f;
    #pragma unroll
    for (int c = 0; c < 16; ++c)
        m = fmaxf(m, part_m[((size_t)(mat * 16 + c)) * N + col]);
    float s = 0.f;
    #pragma unroll
    for (int c = 0; c < 16; ++c) {
        size_t o = ((size_t)(mat * 16 + c)) * N + col;
        s += part_s[o] * __expf(part_m[o] - m);
    }
    m_col[jg] = m;
    isc[jg] = 1.0f / sqrtf(s);
}

__global__ void init_small(double* acc, float* sp, float* sn)
{
    const int idx = blockIdx.x * 256 + threadIdx.x;
    if (idx == 0) *acc = 0.0;
    if (idx < N) { sp[idx] = 0.f; sn[idx] = 0.f; }
}

// ---------------------------------------------------------------------------
// Split-K GEMM with on-the-fly P transform:
//   mat 0: u_part[kc] += Ppos(tile) @ y_pos ; sp += row-sums(Ppos)
//   mat 1: w_part[kc] += Pneg(tile) @ x     ; sn += row-sums(Pneg)
// grid (64, KSPLIT, 2); tile M=64, Nn=128(all), micro-tile 8(m)x4(n).
// ---------------------------------------------------------------------------
__global__ __launch_bounds__(256) void pv_gemm(
    const float* __restrict__ Apos, const float* __restrict__ Aneg,
    const float* __restrict__ y_pos, const float* __restrict__ x,
    const float* __restrict__ m_row, const float* __restrict__ s_row,
    const float* __restrict__ m_col, const float* __restrict__ isc,
    float* __restrict__ u_part, float* __restrict__ w_part,
    float* __restrict__ sp_arr, float* __restrict__ sn_arr)
{
    const int mat = blockIdx.z;
    const float* Amat = mat ? Aneg : Apos;
    const float* B    = mat ? x : y_pos;
    const float* mc   = m_col + mat * N;
    const float* iscm = isc + mat * N;
    float* Cp  = (mat ? w_part : u_part) + (size_t)blockIdx.y * (N * D);
    float* spn = mat ? sn_arr : sp_arr;

    __shared__ float Ps[16][68];
    __shared__ float Ys[16][132];
    __shared__ float red[256];

    const int t = threadIdx.x;
    const int tx = t & 31, my = t >> 5;          // micro-tile: rows my*8.., cols tx*4..
    const int lrow = t >> 2, lkq = (t & 3) << 2; // P staging
    const int br = t >> 5, bc = (t & 31) << 2;   // B staging (rows br, br+8)
    const int bm = blockIdx.x * 64;
    const int kbase = blockIdx.y * (N / KSPLIT);

    const float mr  = m_row[bm + lrow];
    const float isr = 1.0f / sqrtf(s_row[bm + lrow]);

    float acc[8][4] = {};
    float psum = 0.f;

    for (int k0 = kbase; k0 < kbase + N / KSPLIT; k0 += 16) {
        float4 av  = *(const float4*)(Amat + (size_t)(bm + lrow) * N + k0 + lkq);
        float4 mcv = *(const float4*)(mc + k0 + lkq);
        float4 icv = *(const float4*)(iscm + k0 + lkq);
        float4 b0  = *(const float4*)(B + (size_t)(k0 + br) * D + bc);
        float4 b1  = *(const float4*)(B + (size_t)(k0 + br + 8) * D + bc);
        float p0 = __expf(av.x - 0.5f * (mr + mcv.x)) * (isr * icv.x);
        float p1 = __expf(av.y - 0.5f * (mr + mcv.y)) * (isr * icv.y);
        float p2 = __expf(av.z - 0.5f * (mr + mcv.z)) * (isr * icv.z);
        float p3 = __expf(av.w - 0.5f * (mr + mcv.w)) * (isr * icv.w);
        psum += p0 + p1 + p2 + p3;
        __syncthreads();
        Ps[lkq + 0][lrow] = p0; Ps[lkq + 1][lrow] = p1;
        Ps[lkq + 2][lrow] = p2; Ps[lkq + 3][lrow] = p3;
        *(float4*)&Ys[br][bc] = b0;
        *(float4*)&Ys[br + 8][bc] = b1;
        __syncthreads();
        #pragma unroll
        for (int k = 0; k < 16; ++k) {
            float4 a0 = *(const float4*)&Ps[k][my * 8];
            float4 a1 = *(const float4*)&Ps[k][my * 8 + 4];
            float4 b  = *(const float4*)&Ys[k][tx * 4];
            float aa[8] = {a0.x, a0.y, a0.z, a0.w, a1.x, a1.y, a1.z, a1.w};
            #pragma unroll
            for (int im = 0; im < 8; ++im) {
                acc[im][0] = fmaf(aa[im], b.x, acc[im][0]);
                acc[im][1] = fmaf(aa[im], b.y, acc[im][1]);
                acc[im][2] = fmaf(aa[im], b.z, acc[im][2]);
                acc[im][3] = fmaf(aa[im], b.w, acc[im][3]);
            }
        }
    }
    // row-sum contribution (thread's 4 staged values all belong to row bm+lrow)
    red[t] = psum; __syncthreads();
    if ((t & 3) == 0) {
        float s = red[t] + red[t + 1] + red[t + 2] + red[t + 3];
        atomicAdd(&spn[bm + (t >> 2)], s);
    }
    // write partial C tile
    #pragma unroll
    for (int im = 0; im < 8; ++im) {
        const size_t off = (size_t)(bm + my * 8 + im) * D + tx * 4;
        *(float4*)(Cp + off) = make_float4(acc[im][0], acc[im][1], acc[im][2], acc[im][3]);
    }
}

// ---------------------------------------------------------------------------
// Sum split-K partials, V = sn*u - sp*sn*w, accumulate sum(V^2).
// ---------------------------------------------------------------------------
__global__ __launch_bounds__(256) void final_reduce(const float* __restrict__ u_part,
    const float* __restrict__ w_part, const float* __restrict__ sp_arr,
    const float* __restrict__ sn_arr, double* __restrict__ acc_out)
{
    __shared__ float red[256];
    const int t = threadIdx.x;
    const int idx = blockIdx.x * 256 + t;
    float u = 0.f, w = 0.f;
    #pragma unroll
    for (int c = 0; c < KSPLIT; ++c) {
        u += u_part[(size_t)c * (N * D) + idx];
        w += w_part[(size_t)c * (N * D) + idx];
    }
    const int i = idx >> 7;
    const float sn = sn_arr[i];
    const float v = sn * u - sp_arr[i] * sn * w;
    red[t] = v * v; __syncthreads();
    for (int s = 128; s > 0; s >>= 1) { if (t < s) red[t] += red[t + s]; __syncthreads(); }
    if (!t) atomicAdd(acc_out, (double)red[0]);
}

__global__ void finalize(const double* __restrict__ acc, float* __restrict__ out)
{
    out[0] = (float)(*acc * (1.0 / ((double)N * (double)D)));
}

// ---------------------------------------------------------------------------
extern "C" void kernel_launch(void* const* d_in, const int* in_sizes, int n_in,
                              void* d_out, int out_size, void* d_ws, size_t ws_size,
                              hipStream_t stream)
{
    const float* y_pos = (const float*)d_in[0];
    const float* eps   = (const float*)d_in[1];
    const float* W_in  = (const float*)d_in[2];
    const float* b_in  = (const float*)d_in[3];
    const float* W_blk = (const float*)d_in[4];
    const float* b_blk = (const float*)d_in[5];
    const float* W_out = (const float*)d_in[6];
    const float* b_out = (const float*)d_in[7];
    float* out = (float*)d_out;
    (void)in_sizes; (void)n_in; (void)out_size; (void)ws_size;

    double* acc = (double*)d_ws;
    float* base = (float*)d_ws + 4;
    float* x0     = base; base += (size_t)N * H;      // \ after generator these 4M
    float* x1     = base; base += (size_t)N * H;      // / floats are reused as u_part
    float* xo     = base; base += (size_t)N * D;
    float* Apos   = base; base += (size_t)N * N;
    float* Aneg   = base; base += (size_t)N * N;
    float* m_row  = base; base += N;
    float* s_row  = base; base += N;
    float* m_col  = base; base += 2 * N;
    float* isc    = base; base += 2 * N;
    float* nx     = base; base += N;
    float* ny     = base; base += N;
    float* sp     = base; base += N;
    float* sn     = base; base += N;
    float* scratch = base;                             // part_m/part_s then w_part
    float* part_m = scratch;
    float* part_s = scratch + 32 * N;
    float* u_part = x0;                                // 8*N*D = 4M floats = x0+x1
    float* w_part = scratch;                           // 4M floats (after col stats)

    init_small<<<16, 256, 0, stream>>>(acc, sp, sn);

    // --- generator ---
    dim3 gh(H / 64, N / 64);
    gemm_abt<<<gh, 256, 0, stream>>>(eps, W_in, b_in, x0, N, H, D, 0);
    gemm_abt<<<gh, 256, 0, stream>>>(x0, W_blk + 0 * H * H, b_blk + 0 * H, x1, N, H, H, 1);
    gemm_abt<<<gh, 256, 0, stream>>>(x1, W_blk + 1 * H * H, b_blk + 1 * H, x0, N, H, H, 1);
    gemm_abt<<<gh, 256, 0, stream>>>(x0, W_blk + 2 * H * H, b_blk + 2 * H, x1, N, H, H, 1);
    gemm_abt<<<gh, 256, 0, stream>>>(x1, W_blk + 3 * H * H, b_blk + 3 * H, x0, N, H, H, 1);
    gemm_abt<<<dim3(D / 64, N / 64), 256, 0, stream>>>(x0, W_out, b_out, xo, N, D, H, 0);

    // --- norms + distance matrices (a = -d/T) as GEMMs ---
    row_norms<<<dim3(N, 2), 128, 0, stream>>>(xo, y_pos, nx, ny);
    dim3 gd(N / 64, N / 64);
    dist_gemm<<<gd, 256, 0, stream>>>(xo, y_pos, nx, ny, Apos, 0);
    dist_gemm<<<gd, 256, 0, stream>>>(xo, xo, nx, nx, Aneg, 1);

    // --- softmax stats ---
    row_stats<<<N, 256, 0, stream>>>(Apos, Aneg, m_row, s_row);
    col_stats_partial<<<dim3(16, 16, 2), 256, 0, stream>>>(Apos, Aneg, part_m, part_s);
    col_stats_combine<<<32, 256, 0, stream>>>(part_m, part_s, m_col, isc);

    // --- P@V as split-K GEMM (P built on the fly; sp/sn via atomics) ---
    pv_gemm<<<dim3(N / 64, KSPLIT, 2), 256, 0, stream>>>(Apos, Aneg, y_pos, xo,
        m_row, s_row, m_col, isc, u_part, w_part, sp, sn);

    // --- combine partials, V^2 reduction ---
    final_reduce<<<(N * D) / 256, 256, 0, stream>>>(u_part, w_part, sp, sn, acc);
    finalize<<<1, 1, 0, stream>>>(acc, out);
}

// Round 4
// 465.305 us; speedup vs baseline: 2.7910x; 1.3392x over previous
//
#include <hip/hip_runtime.h>
#include <math.h>

#define N 4096
#define D 128
#define H 512
#define INV_T 5.0f
#define KSPLIT 4

typedef short bf16x8 __attribute__((ext_vector_type(8)));
typedef float f32x4 __attribute__((ext_vector_type(4)));
typedef unsigned short u16x8 __attribute__((ext_vector_type(8)));
typedef unsigned short u16;

#define MFMA(a, b, c) __builtin_amdgcn_mfma_f32_16x16x32_bf16((a), (b), (c), 0, 0, 0)

// Split fp32 into hi/lo bf16 (truncation; residual truncated to bf16).
__device__ __forceinline__ void split1(float v, u16& h, u16& l)
{
    unsigned bv = __float_as_uint(v);
    unsigned hb = bv & 0xFFFF0000u;
    float r = v - __uint_as_float(hb);
    h = (u16)(hb >> 16);
    l = (u16)(__float_as_uint(r) >> 16);
}

__device__ __forceinline__ float bf2f(u16 h)
{
    return __uint_as_float(((unsigned)h) << 16);
}

// ---------------------------------------------------------------------------
// One-shot splitter for up to 5 flat fp32 arrays -> bf16 hi/lo.
// ---------------------------------------------------------------------------
struct SplitDesc { const float* src; u16* h; u16* l; int n; };
struct SplitArgs { SplitDesc d[5]; };

__global__ __launch_bounds__(256) void split_multi(SplitArgs args)
{
    SplitDesc de = args.d[blockIdx.y];
    int idx = (blockIdx.x * 256 + threadIdx.x) * 4;
    if (idx >= de.n) return;
    float4 v = *(const float4*)(de.src + idx);
    ushort4 hv, lv;
    split1(v.x, hv.x, lv.x); split1(v.y, hv.y, lv.y);
    split1(v.z, hv.z, lv.z); split1(v.w, hv.w, lv.w);
    *(ushort4*)(de.h + idx) = hv;
    *(ushort4*)(de.l + idx) = lv;
}

// ---------------------------------------------------------------------------
// Transpose+split: fp32 [4096][128] -> bf16 hi/lo [128][4096]. z: 0=X, 1=Y.
// 32x32 tile, 256 threads, ONE float4 slot per thread (256 slots total).
// ---------------------------------------------------------------------------
__global__ __launch_bounds__(256) void transpose_split(
    const float* __restrict__ X, const float* __restrict__ Y,
    u16* __restrict__ Xth, u16* __restrict__ Xtl,
    u16* __restrict__ Yth, u16* __restrict__ Ytl)
{
    const float* src = blockIdx.z ? Y : X;
    u16* th = blockIdx.z ? Yth : Xth;
    u16* tl = blockIdx.z ? Ytl : Xtl;
    __shared__ float tile[32][33];
    const int t = threadIdx.x;
    const int r0 = blockIdx.x * 32, c0 = blockIdx.y * 32;
    {
        int rit = t >> 3, coff = (t & 7) * 4;
        float4 v = *(const float4*)(src + (size_t)(r0 + rit) * D + c0 + coff);
        tile[rit][coff + 0] = v.x; tile[rit][coff + 1] = v.y;
        tile[rit][coff + 2] = v.z; tile[rit][coff + 3] = v.w;
    }
    __syncthreads();
    {
        int cit = t >> 3, roff = (t & 7) * 4;
        ushort4 hv, lv;
        split1(tile[roff + 0][cit], hv.x, lv.x);
        split1(tile[roff + 1][cit], hv.y, lv.y);
        split1(tile[roff + 2][cit], hv.z, lv.z);
        split1(tile[roff + 3][cit], hv.w, lv.w);
        size_t o = (size_t)(c0 + cit) * N + r0 + roff;
        *(ushort4*)(th + o) = hv;
        *(ushort4*)(tl + o) = lv;
    }
}

// ---------------------------------------------------------------------------
// Generator GEMM via split-bf16 MFMA. C = A(MxK) @ B(NnxK)^T + bias,
// resid: C = (Ah+Al) + relu(...). Tile 128(M)x64(N), BK=32, 128 threads
// (2 waves), each wave 64x64. Writes C hi/lo bf16 (+ optional fp32).
// ---------------------------------------------------------------------------
__global__ __launch_bounds__(128) void gen_gemm(
    const u16* __restrict__ Ah, const u16* __restrict__ Al,
    const u16* __restrict__ Bh, const u16* __restrict__ Bl,
    const float* __restrict__ bias,
    float* __restrict__ C, u16* __restrict__ Ch, u16* __restrict__ Cl,
    int M, int Nn, int K, int resid)
{
    __shared__ u16 AhS[128][40], AlS[128][40];
    __shared__ u16 BhS[64][40], BlS[64][40];
    const int t = threadIdx.x;
    const int w = t >> 6, lane = t & 63;
    const int quad = lane >> 4, l16 = lane & 15;
    const int bm = blockIdx.y * 128, bn = blockIdx.x * 64;
    f32x4 acc[4][4] = {};

    for (int k0 = 0; k0 < K; k0 += 32) {
        __syncthreads();
        #pragma unroll
        for (int p = 0; p < 4; ++p) {
            int slot = t + p * 128;
            int row = slot >> 2, koff = (slot & 3) << 3;
            size_t g = (size_t)(bm + row) * K + k0 + koff;
            *(u16x8*)&AhS[row][koff] = *(const u16x8*)(Ah + g);
            *(u16x8*)&AlS[row][koff] = *(const u16x8*)(Al + g);
        }
        #pragma unroll
        for (int p = 0; p < 2; ++p) {
            int slot = t + p * 128;
            int row = slot >> 2, koff = (slot & 3) << 3;
            size_t g = (size_t)(bn + row) * K + k0 + koff;
            *(u16x8*)&BhS[row][koff] = *(const u16x8*)(Bh + g);
            *(u16x8*)&BlS[row][koff] = *(const u16x8*)(Bl + g);
        }
        __syncthreads();
        bf16x8 af[4], alf[4], bhf[4], blf[4];
        #pragma unroll
        for (int mi = 0; mi < 4; ++mi) {
            int r = w * 64 + mi * 16 + l16;
            af[mi]  = *(const bf16x8*)&AhS[r][quad * 8];
            alf[mi] = *(const bf16x8*)&AlS[r][quad * 8];
        }
        #pragma unroll
        for (int ni = 0; ni < 4; ++ni) {
            int r = ni * 16 + l16;
            bhf[ni] = *(const bf16x8*)&BhS[r][quad * 8];
            blf[ni] = *(const bf16x8*)&BlS[r][quad * 8];
        }
        #pragma unroll
        for (int mi = 0; mi < 4; ++mi)
            #pragma unroll
            for (int ni = 0; ni < 4; ++ni) {
                acc[mi][ni] = MFMA(af[mi], bhf[ni], acc[mi][ni]);
                acc[mi][ni] = MFMA(af[mi], blf[ni], acc[mi][ni]);
                acc[mi][ni] = MFMA(alf[mi], bhf[ni], acc[mi][ni]);
            }
    }
    #pragma unroll
    for (int mi = 0; mi < 4; ++mi)
        #pragma unroll
        for (int ni = 0; ni < 4; ++ni)
            #pragma unroll
            for (int r = 0; r < 4; ++r) {
                int gm = bm + w * 64 + mi * 16 + quad * 4 + r;
                int gn = bn + ni * 16 + l16;
                float v = acc[mi][ni][r] + bias[gn];
                if (resid) {
                    size_t o2 = (size_t)gm * K + gn;   // K==Nn for resid layers
                    float prev = bf2f(Ah[o2]) + bf2f(Al[o2]);
                    v = prev + fmaxf(v, 0.0f);
                }
                size_t o = (size_t)gm * Nn + gn;
                if (C) C[o] = v;
                u16 hh, ll; split1(v, hh, ll);
                Ch[o] = hh; Cl[o] = ll;
            }
}

// ---------------------------------------------------------------------------
// Row squared norms of X and Y (fp32).
// ---------------------------------------------------------------------------
__global__ void row_norms(const float* __restrict__ X, const float* __restrict__ Y,
                          float* __restrict__ nx, float* __restrict__ ny)
{
    __shared__ float red[128];
    const float* src = blockIdx.y ? Y : X;
    float* dst = blockIdx.y ? ny : nx;
    const int t = threadIdx.x;
    float v = src[(size_t)blockIdx.x * D + t];
    red[t] = v * v; __syncthreads();
    for (int s = 64; s > 0; s >>= 1) { if (t < s) red[t] += red[t + s]; __syncthreads(); }
    if (!t) dst[blockIdx.x] = red[0];
}

// ---------------------------------------------------------------------------
// Distance via split-bf16 MFMA: Out = -INV_T*sqrt(max(nx+ny-2*X@Y^T,0)).
// Tile 128x128, 256 threads (4 waves in 2x2 quadrants of 64x64). K=D=128.
// ---------------------------------------------------------------------------
__global__ __launch_bounds__(256) void dist_mfma(
    const u16* __restrict__ Xh, const u16* __restrict__ Xl,
    const u16* __restrict__ Yh, const u16* __restrict__ Yl,
    const float* __restrict__ nx, const float* __restrict__ ny,
    float* __restrict__ Out, int self)
{
    __shared__ u16 XhS[128][40], XlS[128][40], YhS[128][40], YlS[128][40];
    const int t = threadIdx.x;
    const int w = t >> 6, lane = t & 63;
    const int quad = lane >> 4, l16 = lane & 15;
    const int wm = w & 1, wn = w >> 1;
    const int bm = blockIdx.y * 128, bn = blockIdx.x * 128;
    f32x4 acc[4][4] = {};

    for (int k0 = 0; k0 < D; k0 += 32) {
        __syncthreads();
        #pragma unroll
        for (int p = 0; p < 2; ++p) {
            int slot = t + p * 256;
            int row = slot >> 2, koff = (slot & 3) << 3;
            size_t gx = (size_t)(bm + row) * D + k0 + koff;
            size_t gy = (size_t)(bn + row) * D + k0 + koff;
            *(u16x8*)&XhS[row][koff] = *(const u16x8*)(Xh + gx);
            *(u16x8*)&XlS[row][koff] = *(const u16x8*)(Xl + gx);
            *(u16x8*)&YhS[row][koff] = *(const u16x8*)(Yh + gy);
            *(u16x8*)&YlS[row][koff] = *(const u16x8*)(Yl + gy);
        }
        __syncthreads();
        bf16x8 af[4], alf[4], bhf[4], blf[4];
        #pragma unroll
        for (int mi = 0; mi < 4; ++mi) {
            int r = wm * 64 + mi * 16 + l16;
            af[mi]  = *(const bf16x8*)&XhS[r][quad * 8];
            alf[mi] = *(const bf16x8*)&XlS[r][quad * 8];
        }
        #pragma unroll
        for (int ni = 0; ni < 4; ++ni) {
            int r = wn * 64 + ni * 16 + l16;
            bhf[ni] = *(const bf16x8*)&YhS[r][quad * 8];
            blf[ni] = *(const bf16x8*)&YlS[r][quad * 8];
        }
        #pragma unroll
        for (int mi = 0; mi < 4; ++mi)
            #pragma unroll
            for (int ni = 0; ni < 4; ++ni) {
                acc[mi][ni] = MFMA(af[mi], bhf[ni], acc[mi][ni]);
                acc[mi][ni] = MFMA(af[mi], blf[ni], acc[mi][ni]);
                acc[mi][ni] = MFMA(alf[mi], bhf[ni], acc[mi][ni]);
            }
    }
    #pragma unroll
    for (int mi = 0; mi < 4; ++mi)
        #pragma unroll
        for (int r = 0; r < 4; ++r) {
            int gm = bm + wm * 64 + mi * 16 + quad * 4 + r;
            float nxm = nx[gm];
            #pragma unroll
            for (int ni = 0; ni < 4; ++ni) {
                int gn = bn + wn * 64 + ni * 16 + l16;
                float d2 = nxm + ny[gn] - 2.0f * acc[mi][ni][r];
                float a = -sqrtf(fmaxf(d2, 0.0f)) * INV_T;
                if (self && gm == gn) a = -5.0e6f;
                Out[(size_t)gm * N + gn] = a;
            }
        }
}

// ---------------------------------------------------------------------------
// Online row stats over concatenated [Apos_row, Aneg_row]: (max, sum-exp)
// ---------------------------------------------------------------------------
__global__ __launch_bounds__(256) void row_stats(const float* __restrict__ Apos,
    const float* __restrict__ Aneg, float* __restrict__ m_row, float* __restrict__ s_row)
{
    const int i = blockIdx.x, t = threadIdx.x;
    __shared__ float rm[256], rs[256];
    const float* rp = Apos + (size_t)i * N;
    const float* rn = Aneg + (size_t)i * N;
    float m = -3.0e38f, s = 0.f;
    for (int j = t; j < N; j += 256) {
        float a = rp[j];
        float mn = fmaxf(m, a); s = s * __expf(m - mn) + __expf(a - mn); m = mn;
        a = rn[j];
        mn = fmaxf(m, a); s = s * __expf(m - mn) + __expf(a - mn); m = mn;
    }
    rm[t] = m; rs[t] = s; __syncthreads();
    for (int st = 128; st > 0; st >>= 1) {
        if (t < st) {
            float m2 = rm[t + st], s2 = rs[t + st];
            float mn = fmaxf(rm[t], m2);
            rs[t] = rs[t] * __expf(rm[t] - mn) + s2 * __expf(m2 - mn);
            rm[t] = mn;
        }
        __syncthreads();
    }
    if (!t) { m_row[i] = rm[0]; s_row[i] = rs[0]; }
}

// ---------------------------------------------------------------------------
// Column stats: online partials over 256-row chunks, then combine.
// ---------------------------------------------------------------------------
__global__ __launch_bounds__(256) void col_stats_partial(const float* __restrict__ Apos,
    const float* __restrict__ Aneg, float* __restrict__ part_m, float* __restrict__ part_s)
{
    const int col = blockIdx.x * 256 + threadIdx.x;
    const int chunk = blockIdx.y;
    const int mat = blockIdx.z;
    const float* Asrc = mat ? Aneg : Apos;
    const int r0 = chunk * 256;
    float m = -3.0e38f, s = 0.f;
    #pragma unroll 4
    for (int r = 0; r < 256; ++r) {
        float a = Asrc[(size_t)(r0 + r) * N + col];
        float mn = fmaxf(m, a);
        s = s * __expf(m - mn) + __expf(a - mn);
        m = mn;
    }
    const size_t o = ((size_t)(mat * 16 + chunk)) * N + col;
    part_m[o] = m;
    part_s[o] = s;
}

__global__ __launch_bounds__(256) void col_stats_combine(const float* __restrict__ part_m,
    const float* __restrict__ part_s, float* __restrict__ m_col, float* __restrict__ isc)
{
    const int jg = blockIdx.x * 256 + threadIdx.x;
    const int mat = jg >> 12;
    const int col = jg & (N - 1);
    float m = -3.0e38f;
    #pragma unroll
    for (int c = 0; c < 16; ++c)
        m = fmaxf(m, part_m[((size_t)(mat * 16 + c)) * N + col]);
    float s = 0.f;
    #pragma unroll
    for (int c = 0; c < 16; ++c) {
        size_t o = ((size_t)(mat * 16 + c)) * N + col;
        s += part_s[o] * __expf(part_m[o] - m);
    }
    m_col[jg] = m;
    isc[jg] = 1.0f / sqrtf(s);
}

__global__ void init_small(double* acc, float* sp, float* sn)
{
    const int idx = blockIdx.x * 256 + threadIdx.x;
    if (idx == 0) *acc = 0.0;
    if (idx < N) { sp[idx] = 0.f; sn[idx] = 0.f; }
}

// ---------------------------------------------------------------------------
// pv via MFMA: per (i-tile 64, j-chunk N/KSPLIT, mat). Load A fp32 tile,
// transform to P (fp32 rowsums -> sp/sn), split to bf16 hi/lo in LDS,
// MFMA P @ B with pre-transposed bf16 B ([d][j]). O partial -> u/w_part.
// ---------------------------------------------------------------------------
__global__ __launch_bounds__(256) void pv_mfma(
    const float* __restrict__ Apos, const float* __restrict__ Aneg,
    const u16* __restrict__ Yth, const u16* __restrict__ Ytl,
    const u16* __restrict__ Xth, const u16* __restrict__ Xtl,
    const float* __restrict__ m_row, const float* __restrict__ s_row,
    const float* __restrict__ m_col, const float* __restrict__ isc,
    float* __restrict__ u_part, float* __restrict__ w_part,
    float* __restrict__ sp_arr, float* __restrict__ sn_arr)
{
    const int mat = blockIdx.z;
    const float* Am = mat ? Aneg : Apos;
    const u16* Bh = mat ? Xth : Yth;
    const u16* Bl = mat ? Xtl : Ytl;
    const float* mc = m_col + mat * N;
    const float* ic = isc + mat * N;
    float* Cp = (mat ? w_part : u_part) + (size_t)blockIdx.y * (N * D);
    float* spn = mat ? sn_arr : sp_arr;

    __shared__ u16 BhS[128][72], BlS[128][72];
    __shared__ u16 PhS[64][72], PlS[64][72];
    __shared__ float mrS[64], isrS[64];

    const int t = threadIdx.x;
    const int w = t >> 6, lane = t & 63;
    const int quad = lane >> 4, l16 = lane & 15;
    const int bm = blockIdx.x * 64;
    const int jbase = blockIdx.y * (N / KSPLIT);
    const int arow = t >> 4;          // 0..15
    const int aj = (t & 15) << 2;     // 0..60

    if (t < 64) { mrS[t] = m_row[bm + t]; isrS[t] = 1.0f / sqrtf(s_row[bm + t]); }

    f32x4 acc[8] = {};
    float rs[4] = {0.f, 0.f, 0.f, 0.f};

    for (int jt = 0; jt < (N / KSPLIT) / 64; ++jt) {
        const int j0 = jbase + jt * 64;
        __syncthreads();   // protect previous iteration's LDS reads (+ mrS init)
        #pragma unroll
        for (int p = 0; p < 4; ++p) {
            int slot = t + p * 256;
            int d = slot >> 3, joff = (slot & 7) << 3;
            size_t g = (size_t)d * N + j0 + joff;
            *(u16x8*)&BhS[d][joff] = *(const u16x8*)(Bh + g);
            *(u16x8*)&BlS[d][joff] = *(const u16x8*)(Bl + g);
        }
        float4 mcv = *(const float4*)(mc + j0 + aj);
        float4 icv = *(const float4*)(ic + j0 + aj);
        #pragma unroll
        for (int s = 0; s < 4; ++s) {
            int row = arow + s * 16;
            float4 av = *(const float4*)(Am + (size_t)(bm + row) * N + j0 + aj);
            float mr = mrS[row], isr = isrS[row];
            float p0 = __expf(av.x - 0.5f * (mr + mcv.x)) * (isr * icv.x);
            float p1 = __expf(av.y - 0.5f * (mr + mcv.y)) * (isr * icv.y);
            float p2 = __expf(av.z - 0.5f * (mr + mcv.z)) * (isr * icv.z);
            float p3 = __expf(av.w - 0.5f * (mr + mcv.w)) * (isr * icv.w);
            rs[s] += p0 + p1 + p2 + p3;
            ushort4 hv, lv;
            split1(p0, hv.x, lv.x); split1(p1, hv.y, lv.y);
            split1(p2, hv.z, lv.z); split1(p3, hv.w, lv.w);
            *(ushort4*)&PhS[row][aj] = hv;
            *(ushort4*)&PlS[row][aj] = lv;
        }
        __syncthreads();
        #pragma unroll
        for (int ks = 0; ks < 2; ++ks) {
            const int kk = ks * 32 + quad * 8;
            bf16x8 ph = *(const bf16x8*)&PhS[w * 16 + l16][kk];
            bf16x8 pl = *(const bf16x8*)&PlS[w * 16 + l16][kk];
            #pragma unroll
            for (int ni = 0; ni < 8; ++ni) {
                bf16x8 bh = *(const bf16x8*)&BhS[ni * 16 + l16][kk];
                bf16x8 bl = *(const bf16x8*)&BlS[ni * 16 + l16][kk];
                acc[ni] = MFMA(ph, bh, acc[ni]);
                acc[ni] = MFMA(pl, bh, acc[ni]);
                acc[ni] = MFMA(ph, bl, acc[ni]);
            }
        }
    }
    #pragma unroll
    for (int ni = 0; ni < 8; ++ni)
        #pragma unroll
        for (int r = 0; r < 4; ++r) {
            int row = w * 16 + quad * 4 + r;
            int col = ni * 16 + l16;
            Cp[(size_t)(bm + row) * D + col] = acc[ni][r];
        }
    #pragma unroll
    for (int s = 0; s < 4; ++s) {
        float v = rs[s];
        v += __shfl_xor(v, 1); v += __shfl_xor(v, 2);
        v += __shfl_xor(v, 4); v += __shfl_xor(v, 8);
        if (l16 == 0) atomicAdd(&spn[bm + arow + s * 16], v);
    }
}

// ---------------------------------------------------------------------------
// Sum split-K partials, V = sn*u - sp*sn*w, accumulate sum(V^2).
// ---------------------------------------------------------------------------
__global__ __launch_bounds__(256) void final_reduce(const float* __restrict__ u_part,
    const float* __restrict__ w_part, const float* __restrict__ sp_arr,
    const float* __restrict__ sn_arr, double* __restrict__ acc_out)
{
    __shared__ float red[256];
    const int t = threadIdx.x;
    const int idx = blockIdx.x * 256 + t;
    float u = 0.f, w = 0.f;
    #pragma unroll
    for (int c = 0; c < KSPLIT; ++c) {
        u += u_part[(size_t)c * (N * D) + idx];
        w += w_part[(size_t)c * (N * D) + idx];
    }
    const int i = idx >> 7;
    const float sn = sn_arr[i];
    const float v = sn * u - sp_arr[i] * sn * w;
    red[t] = v * v; __syncthreads();
    for (int s = 128; s > 0; s >>= 1) { if (t < s) red[t] += red[t + s]; __syncthreads(); }
    if (!t) atomicAdd(acc_out, (double)red[0]);
}

__global__ void finalize(const double* __restrict__ acc, float* __restrict__ out)
{
    out[0] = (float)(*acc * (1.0 / ((double)N * (double)D)));
}

// ---------------------------------------------------------------------------
extern "C" void kernel_launch(void* const* d_in, const int* in_sizes, int n_in,
                              void* d_out, int out_size, void* d_ws, size_t ws_size,
                              hipStream_t stream)
{
    const float* y_pos = (const float*)d_in[0];
    const float* eps   = (const float*)d_in[1];
    const float* W_in  = (const float*)d_in[2];
    const float* b_in  = (const float*)d_in[3];
    const float* W_blk = (const float*)d_in[4];
    const float* b_blk = (const float*)d_in[5];
    const float* W_out = (const float*)d_in[6];
    const float* b_out = (const float*)d_in[7];
    float* out = (float*)d_out;
    (void)in_sizes; (void)n_in; (void)out_size; (void)ws_size;

    char* p = (char*)d_ws;
    auto alloc = [&](size_t bytes) {
        char* r = p;
        p += (bytes + 255) & ~(size_t)255;
        return r;
    };
    // --- small arrays (~0.2 MB) ---
    double* acc  = (double*)alloc(8);
    float* sp     = (float*)alloc(N * 4);
    float* sn     = (float*)alloc(N * 4);
    float* m_row  = (float*)alloc(N * 4);
    float* s_row  = (float*)alloc(N * 4);
    float* m_col  = (float*)alloc(2 * N * 4);
    float* isc    = (float*)alloc(2 * N * 4);
    float* nx     = (float*)alloc(N * 4);
    float* ny     = (float*)alloc(N * 4);
    // --- 2 MB region: eh/el (early) aliased with part_m/part_s (late) ---
    char* pmreg   = alloc(2 * 1024 * 1024);
    u16* eh       = (u16*)pmreg;                 // N*D*2 = 1 MB
    u16* el       = eh + (size_t)N * D;          // 1 MB
    float* part_m = (float*)pmreg;               // 32*N*4 = 0.5 MB
    float* part_s = part_m + 32 * N;             // 0.5 MB
    // --- xo fp32 (2 MB) + bf16 x/y arrays (8 MB) ---
    float* xo  = (float*)alloc((size_t)N * D * 4);
    u16* xh    = (u16*)alloc((size_t)N * D * 2);
    u16* xl    = (u16*)alloc((size_t)N * D * 2);
    u16* xth   = (u16*)alloc((size_t)N * D * 2);
    u16* xtl   = (u16*)alloc((size_t)N * D * 2);
    u16* yh    = (u16*)alloc((size_t)N * D * 2);
    u16* yl    = (u16*)alloc((size_t)N * D * 2);
    u16* yth   = (u16*)alloc((size_t)N * D * 2);
    u16* ytl   = (u16*)alloc((size_t)N * D * 2);
    // --- generator region (20.5 MB): activations hi/lo + weights; reused as
    //     u_part/w_part (KSPLIT*N*D*4 each = 16 MB total) after generator ---
    char* genreg = alloc((size_t)(4 * (size_t)N * H * 2       // x0h/l, x1h/l
                                + 2 * (size_t)H * D * 2       // wih/wil
                                + 2 * (size_t)4 * H * H * 2   // wbh/wbl
                                + 2 * (size_t)D * H * 2));    // woh/wol
    u16* x0h = (u16*)genreg;
    u16* x0l = x0h + (size_t)N * H;
    u16* x1h = x0l + (size_t)N * H;
    u16* x1l = x1h + (size_t)N * H;
    u16* wih = x1l + (size_t)N * H;
    u16* wil = wih + (size_t)H * D;
    u16* wbh = wil + (size_t)H * D;
    u16* wbl = wbh + (size_t)4 * H * H;
    u16* woh = wbl + (size_t)4 * H * H;
    u16* wol = woh + (size_t)D * H;
    float* u_part = (float*)genreg;                      // KSPLIT*N*D = 8 MB
    float* w_part = u_part + (size_t)KSPLIT * N * D;     // 8 MB
    // --- the big ones (128 MB) ---
    float* Apos = (float*)alloc((size_t)N * N * 4);
    float* Aneg = (float*)alloc((size_t)N * N * 4);

    init_small<<<16, 256, 0, stream>>>(acc, sp, sn);

    // --- split inputs/weights to bf16 hi/lo ---
    SplitArgs sa;
    sa.d[0] = { eps,   eh,  el,  N * D };
    sa.d[1] = { y_pos, yh,  yl,  N * D };
    sa.d[2] = { W_in,  wih, wil, H * D };
    sa.d[3] = { W_blk, wbh, wbl, 4 * H * H };
    sa.d[4] = { W_out, woh, wol, D * H };
    split_multi<<<dim3(1024, 5), 256, 0, stream>>>(sa);

    // --- generator (MFMA split-bf16); activations live as hi/lo pairs ---
    dim3 gh(H / 64, N / 128);
    gen_gemm<<<gh, 128, 0, stream>>>(eh, el, wih, wil, b_in,
                                     nullptr, x0h, x0l, N, H, D, 0);
    gen_gemm<<<gh, 128, 0, stream>>>(x0h, x0l, wbh + 0 * H * H, wbl + 0 * H * H,
                                     b_blk + 0 * H, nullptr, x1h, x1l, N, H, H, 1);
    gen_gemm<<<gh, 128, 0, stream>>>(x1h, x1l, wbh + 1 * H * H, wbl + 1 * H * H,
                                     b_blk + 1 * H, nullptr, x0h, x0l, N, H, H, 1);
    gen_gemm<<<gh, 128, 0, stream>>>(x0h, x0l, wbh + 2 * H * H, wbl + 2 * H * H,
                                     b_blk + 2 * H, nullptr, x1h, x1l, N, H, H, 1);
    gen_gemm<<<gh, 128, 0, stream>>>(x1h, x1l, wbh + 3 * H * H, wbl + 3 * H * H,
                                     b_blk + 3 * H, nullptr, x0h, x0l, N, H, H, 1);
    gen_gemm<<<dim3(D / 64, N / 128), 128, 0, stream>>>(x0h, x0l, woh, wol, b_out,
                                     xo, xh, xl, N, D, H, 0);

    // --- norms + transposed splits ---
    row_norms<<<dim3(N, 2), 128, 0, stream>>>(xo, y_pos, nx, ny);
    transpose_split<<<dim3(N / 32, D / 32, 2), 256, 0, stream>>>(
        xo, y_pos, xth, xtl, yth, ytl);

    // --- distance matrices via MFMA ---
    dim3 gd(N / 128, N / 128);
    dist_mfma<<<gd, 256, 0, stream>>>(xh, xl, yh, yl, nx, ny, Apos, 0);
    dist_mfma<<<gd, 256, 0, stream>>>(xh, xl, xh, xl, nx, nx, Aneg, 1);

    // --- softmax stats ---
    row_stats<<<N, 256, 0, stream>>>(Apos, Aneg, m_row, s_row);
    col_stats_partial<<<dim3(16, 16, 2), 256, 0, stream>>>(Apos, Aneg, part_m, part_s);
    col_stats_combine<<<32, 256, 0, stream>>>(part_m, part_s, m_col, isc);

    // --- P@V via MFMA (P built on the fly; sp/sn fp32 via atomics) ---
    pv_mfma<<<dim3(N / 64, KSPLIT, 2), 256, 0, stream>>>(Apos, Aneg,
        yth, ytl, xth, xtl, m_row, s_row, m_col, isc, u_part, w_part, sp, sn);

    // --- combine partials, V^2 reduction ---
    final_reduce<<<(N * D) / 256, 256, 0, stream>>>(u_part, w_part, sp, sn, acc);
    finalize<<<1, 1, 0, stream>>>(acc, out);
}

// Round 5
// 438.725 us; speedup vs baseline: 2.9601x; 1.0606x over previous
//
#include <hip/hip_runtime.h>
#include <math.h>

#define N 4096
#define D 128
#define H 512
#define INV_T 5.0f
#define KSPLIT 4

typedef short bf16x8 __attribute__((ext_vector_type(8)));
typedef float f32x4 __attribute__((ext_vector_type(4)));
typedef unsigned short u16x8 __attribute__((ext_vector_type(8)));
typedef unsigned short u16;

#define MFMA(a, b, c) __builtin_amdgcn_mfma_f32_16x16x32_bf16((a), (b), (c), 0, 0, 0)

// Split fp32 into hi/lo bf16 (truncation; residual truncated to bf16).
__device__ __forceinline__ void split1(float v, u16& h, u16& l)
{
    unsigned bv = __float_as_uint(v);
    unsigned hb = bv & 0xFFFF0000u;
    float r = v - __uint_as_float(hb);
    h = (u16)(hb >> 16);
    l = (u16)(__float_as_uint(r) >> 16);
}

__device__ __forceinline__ float bf2f(u16 h)
{
    return __uint_as_float(((unsigned)h) << 16);
}

// Round-to-nearest-even bf16 (unbiased — used for pv's B operand).
__device__ __forceinline__ u16 rtn_bf16(float v)
{
    unsigned u = __float_as_uint(v);
    return (u16)((u + 0x7FFFu + ((u >> 16) & 1u)) >> 16);
}

// ---------------------------------------------------------------------------
// One-shot splitter for up to 5 flat fp32 arrays -> bf16 hi/lo.
// ---------------------------------------------------------------------------
struct SplitDesc { const float* src; u16* h; u16* l; int n; };
struct SplitArgs { SplitDesc d[5]; };

__global__ __launch_bounds__(256) void split_multi(SplitArgs args)
{
    SplitDesc de = args.d[blockIdx.y];
    int idx = (blockIdx.x * 256 + threadIdx.x) * 4;
    if (idx >= de.n) return;
    float4 v = *(const float4*)(de.src + idx);
    ushort4 hv, lv;
    split1(v.x, hv.x, lv.x); split1(v.y, hv.y, lv.y);
    split1(v.z, hv.z, lv.z); split1(v.w, hv.w, lv.w);
    *(ushort4*)(de.h + idx) = hv;
    *(ushort4*)(de.l + idx) = lv;
}

// ---------------------------------------------------------------------------
// Transpose + RTN-bf16: fp32 [4096][128] -> bf16 [128][4096]. z: 0=X, 1=Y.
// 32x32 tile, 256 threads, one float4 slot per thread.
// ---------------------------------------------------------------------------
__global__ __launch_bounds__(256) void transpose_rtn(
    const float* __restrict__ X, const float* __restrict__ Y,
    u16* __restrict__ Xth, u16* __restrict__ Yth)
{
    const float* src = blockIdx.z ? Y : X;
    u16* th = blockIdx.z ? Yth : Xth;
    __shared__ float tile[32][33];
    const int t = threadIdx.x;
    const int r0 = blockIdx.x * 32, c0 = blockIdx.y * 32;
    {
        int rit = t >> 3, coff = (t & 7) * 4;
        float4 v = *(const float4*)(src + (size_t)(r0 + rit) * D + c0 + coff);
        tile[rit][coff + 0] = v.x; tile[rit][coff + 1] = v.y;
        tile[rit][coff + 2] = v.z; tile[rit][coff + 3] = v.w;
    }
    __syncthreads();
    {
        int cit = t >> 3, roff = (t & 7) * 4;
        ushort4 hv;
        hv.x = rtn_bf16(tile[roff + 0][cit]);
        hv.y = rtn_bf16(tile[roff + 1][cit]);
        hv.z = rtn_bf16(tile[roff + 2][cit]);
        hv.w = rtn_bf16(tile[roff + 3][cit]);
        *(ushort4*)(th + (size_t)(c0 + cit) * N + r0 + roff) = hv;
    }
}

// ---------------------------------------------------------------------------
// Generator GEMM via split-bf16 MFMA. C = A(MxK) @ B(NnxK)^T + bias,
// resid: C = (Ah+Al) + relu(...). Tile 128(M)x64(N), BK=32, 128 threads.
// ---------------------------------------------------------------------------
__global__ __launch_bounds__(128) void gen_gemm(
    const u16* __restrict__ Ah, const u16* __restrict__ Al,
    const u16* __restrict__ Bh, const u16* __restrict__ Bl,
    const float* __restrict__ bias,
    float* __restrict__ C, u16* __restrict__ Ch, u16* __restrict__ Cl,
    int M, int Nn, int K, int resid)
{
    __shared__ u16 AhS[128][40], AlS[128][40];
    __shared__ u16 BhS[64][40], BlS[64][40];
    const int t = threadIdx.x;
    const int w = t >> 6, lane = t & 63;
    const int quad = lane >> 4, l16 = lane & 15;
    const int bm = blockIdx.y * 128, bn = blockIdx.x * 64;
    f32x4 acc[4][4] = {};

    for (int k0 = 0; k0 < K; k0 += 32) {
        __syncthreads();
        #pragma unroll
        for (int p = 0; p < 4; ++p) {
            int slot = t + p * 128;
            int row = slot >> 2, koff = (slot & 3) << 3;
            size_t g = (size_t)(bm + row) * K + k0 + koff;
            *(u16x8*)&AhS[row][koff] = *(const u16x8*)(Ah + g);
            *(u16x8*)&AlS[row][koff] = *(const u16x8*)(Al + g);
        }
        #pragma unroll
        for (int p = 0; p < 2; ++p) {
            int slot = t + p * 128;
            int row = slot >> 2, koff = (slot & 3) << 3;
            size_t g = (size_t)(bn + row) * K + k0 + koff;
            *(u16x8*)&BhS[row][koff] = *(const u16x8*)(Bh + g);
            *(u16x8*)&BlS[row][koff] = *(const u16x8*)(Bl + g);
        }
        __syncthreads();
        bf16x8 af[4], alf[4], bhf[4], blf[4];
        #pragma unroll
        for (int mi = 0; mi < 4; ++mi) {
            int r = w * 64 + mi * 16 + l16;
            af[mi]  = *(const bf16x8*)&AhS[r][quad * 8];
            alf[mi] = *(const bf16x8*)&AlS[r][quad * 8];
        }
        #pragma unroll
        for (int ni = 0; ni < 4; ++ni) {
            int r = ni * 16 + l16;
            bhf[ni] = *(const bf16x8*)&BhS[r][quad * 8];
            blf[ni] = *(const bf16x8*)&BlS[r][quad * 8];
        }
        #pragma unroll
        for (int mi = 0; mi < 4; ++mi)
            #pragma unroll
            for (int ni = 0; ni < 4; ++ni) {
                acc[mi][ni] = MFMA(af[mi], bhf[ni], acc[mi][ni]);
                acc[mi][ni] = MFMA(af[mi], blf[ni], acc[mi][ni]);
                acc[mi][ni] = MFMA(alf[mi], bhf[ni], acc[mi][ni]);
            }
    }
    #pragma unroll
    for (int mi = 0; mi < 4; ++mi)
        #pragma unroll
        for (int ni = 0; ni < 4; ++ni)
            #pragma unroll
            for (int r = 0; r < 4; ++r) {
                int gm = bm + w * 64 + mi * 16 + quad * 4 + r;
                int gn = bn + ni * 16 + l16;
                float v = acc[mi][ni][r] + bias[gn];
                if (resid) {
                    size_t o2 = (size_t)gm * K + gn;   // K==Nn for resid layers
                    float prev = bf2f(Ah[o2]) + bf2f(Al[o2]);
                    v = prev + fmaxf(v, 0.0f);
                }
                size_t o = (size_t)gm * Nn + gn;
                if (C) C[o] = v;
                u16 hh, ll; split1(v, hh, ll);
                Ch[o] = hh; Cl[o] = ll;
            }
}

// ---------------------------------------------------------------------------
// Row squared norms of X and Y (fp32).
// ---------------------------------------------------------------------------
__global__ void row_norms(const float* __restrict__ X, const float* __restrict__ Y,
                          float* __restrict__ nx, float* __restrict__ ny)
{
    __shared__ float red[128];
    const float* src = blockIdx.y ? Y : X;
    float* dst = blockIdx.y ? ny : nx;
    const int t = threadIdx.x;
    float v = src[(size_t)blockIdx.x * D + t];
    red[t] = v * v; __syncthreads();
    for (int s = 64; s > 0; s >>= 1) { if (t < s) red[t] += red[t + s]; __syncthreads(); }
    if (!t) dst[blockIdx.x] = red[0];
}

// ---------------------------------------------------------------------------
// Distance via split-bf16 MFMA, FUSED with per-tile softmax partial stats.
// Out = -INV_T*sqrt(max(nx+ny-2*X@Y^T,0)); diag(self) -> -5e6.
// Row partials: (m,s) over 64-col slabs -> prm/prs[ctile(64)][row].
// Col partials: (m,s) over 64-row slabs -> pcm/pcs[rtile(64)][col].
// ---------------------------------------------------------------------------
__global__ __launch_bounds__(256) void dist_fused(
    const u16* __restrict__ Xh, const u16* __restrict__ Xl,
    const u16* __restrict__ Yh, const u16* __restrict__ Yl,
    const float* __restrict__ nx, const float* __restrict__ ny,
    float* __restrict__ Out,
    float* __restrict__ prm, float* __restrict__ prs,
    float* __restrict__ pcm, float* __restrict__ pcs, int self)
{
    __shared__ u16 XhS[128][40], XlS[128][40], YhS[128][40], YlS[128][40];
    const int t = threadIdx.x;
    const int w = t >> 6, lane = t & 63;
    const int quad = lane >> 4, l16 = lane & 15;
    const int wm = w & 1, wn = w >> 1;
    const int bm = blockIdx.y * 128, bn = blockIdx.x * 128;
    f32x4 acc[4][4] = {};

    for (int k0 = 0; k0 < D; k0 += 32) {
        __syncthreads();
        #pragma unroll
        for (int p = 0; p < 2; ++p) {
            int slot = t + p * 256;
            int row = slot >> 2, koff = (slot & 3) << 3;
            size_t gx = (size_t)(bm + row) * D + k0 + koff;
            size_t gy = (size_t)(bn + row) * D + k0 + koff;
            *(u16x8*)&XhS[row][koff] = *(const u16x8*)(Xh + gx);
            *(u16x8*)&XlS[row][koff] = *(const u16x8*)(Xl + gx);
            *(u16x8*)&YhS[row][koff] = *(const u16x8*)(Yh + gy);
            *(u16x8*)&YlS[row][koff] = *(const u16x8*)(Yl + gy);
        }
        __syncthreads();
        bf16x8 af[4], alf[4], bhf[4], blf[4];
        #pragma unroll
        for (int mi = 0; mi < 4; ++mi) {
            int r = wm * 64 + mi * 16 + l16;
            af[mi]  = *(const bf16x8*)&XhS[r][quad * 8];
            alf[mi] = *(const bf16x8*)&XlS[r][quad * 8];
        }
        #pragma unroll
        for (int ni = 0; ni < 4; ++ni) {
            int r = wn * 64 + ni * 16 + l16;
            bhf[ni] = *(const bf16x8*)&YhS[r][quad * 8];
            blf[ni] = *(const bf16x8*)&YlS[r][quad * 8];
        }
        #pragma unroll
        for (int mi = 0; mi < 4; ++mi)
            #pragma unroll
            for (int ni = 0; ni < 4; ++ni) {
                acc[mi][ni] = MFMA(af[mi], bhf[ni], acc[mi][ni]);
                acc[mi][ni] = MFMA(af[mi], blf[ni], acc[mi][ni]);
                acc[mi][ni] = MFMA(alf[mi], bhf[ni], acc[mi][ni]);
            }
    }
    // --- transform in place: acc -> a = -5*sqrt(d2); write A ---
    #pragma unroll
    for (int mi = 0; mi < 4; ++mi)
        #pragma unroll
        for (int r = 0; r < 4; ++r) {
            int gm = bm + wm * 64 + mi * 16 + quad * 4 + r;
            float nxm = nx[gm];
            #pragma unroll
            for (int ni = 0; ni < 4; ++ni) {
                int gn = bn + wn * 64 + ni * 16 + l16;
                float d2 = nxm + ny[gn] - 2.0f * acc[mi][ni][r];
                float a = -sqrtf(fmaxf(d2, 0.0f)) * INV_T;
                if (self && gm == gn) a = -5.0e6f;
                acc[mi][ni][r] = a;
                Out[(size_t)gm * N + gn] = a;
            }
        }
    // --- row partials: per (mi,r), reduce over ni (in-lane) + l16 (shfl) ---
    const int ct = blockIdx.x * 2 + wn;
    #pragma unroll
    for (int mi = 0; mi < 4; ++mi)
        #pragma unroll
        for (int r = 0; r < 4; ++r) {
            float m = fmaxf(fmaxf(acc[mi][0][r], acc[mi][1][r]),
                            fmaxf(acc[mi][2][r], acc[mi][3][r]));
            m = fmaxf(m, __shfl_xor(m, 1));
            m = fmaxf(m, __shfl_xor(m, 2));
            m = fmaxf(m, __shfl_xor(m, 4));
            m = fmaxf(m, __shfl_xor(m, 8));
            float s = __expf(acc[mi][0][r] - m) + __expf(acc[mi][1][r] - m)
                    + __expf(acc[mi][2][r] - m) + __expf(acc[mi][3][r] - m);
            s += __shfl_xor(s, 1); s += __shfl_xor(s, 2);
            s += __shfl_xor(s, 4); s += __shfl_xor(s, 8);
            if (l16 == 0) {
                int grow = bm + wm * 64 + mi * 16 + quad * 4 + r;
                prm[(size_t)ct * N + grow] = m;
                prs[(size_t)ct * N + grow] = s;
            }
        }
    // --- col partials: per ni, reduce over (mi,r) in-lane + quad (shfl) ---
    const int rt = blockIdx.y * 2 + wm;
    #pragma unroll
    for (int ni = 0; ni < 4; ++ni) {
        float m = -3.0e38f;
        #pragma unroll
        for (int mi = 0; mi < 4; ++mi)
            #pragma unroll
            for (int r = 0; r < 4; ++r)
                m = fmaxf(m, acc[mi][ni][r]);
        m = fmaxf(m, __shfl_xor(m, 16));
        m = fmaxf(m, __shfl_xor(m, 32));
        float s = 0.f;
        #pragma unroll
        for (int mi = 0; mi < 4; ++mi)
            #pragma unroll
            for (int r = 0; r < 4; ++r)
                s += __expf(acc[mi][ni][r] - m);
        s += __shfl_xor(s, 16);
        s += __shfl_xor(s, 32);
        if (quad == 0) {
            int gcol = bn + wn * 64 + ni * 16 + l16;
            pcm[(size_t)rt * N + gcol] = m;
            pcs[(size_t)rt * N + gcol] = s;
        }
    }
}

// ---------------------------------------------------------------------------
// Combine partials: idx<N -> row stats (pos+neg, 128 partials);
// else -> col stats for pos (idx<2N) / neg (idx<3N), 64 partials each.
// ---------------------------------------------------------------------------
__global__ __launch_bounds__(256) void stats_combine(
    const float* __restrict__ prm_p, const float* __restrict__ prs_p,
    const float* __restrict__ prm_n, const float* __restrict__ prs_n,
    const float* __restrict__ pcm_p, const float* __restrict__ pcs_p,
    const float* __restrict__ pcm_n, const float* __restrict__ pcs_n,
    float* __restrict__ m_row, float* __restrict__ isr,
    float* __restrict__ m_col, float* __restrict__ isc)
{
    const int idx = blockIdx.x * 256 + threadIdx.x;
    if (idx < N) {
        const int i = idx;
        float m = -3.0e38f;
        for (int c = 0; c < 64; ++c) {
            m = fmaxf(m, prm_p[(size_t)c * N + i]);
            m = fmaxf(m, prm_n[(size_t)c * N + i]);
        }
        float s = 0.f;
        for (int c = 0; c < 64; ++c) {
            s += prs_p[(size_t)c * N + i] * __expf(prm_p[(size_t)c * N + i] - m);
            s += prs_n[(size_t)c * N + i] * __expf(prm_n[(size_t)c * N + i] - m);
        }
        m_row[i] = m;
        isr[i] = 1.0f / sqrtf(s);
    } else {
        const int mat = (idx - N) >> 12;
        const int j = idx & (N - 1);
        const float* pm = mat ? pcm_n : pcm_p;
        const float* ps = mat ? pcs_n : pcs_p;
        float m = -3.0e38f;
        for (int c = 0; c < 64; ++c)
            m = fmaxf(m, pm[(size_t)c * N + j]);
        float s = 0.f;
        for (int c = 0; c < 64; ++c)
            s += ps[(size_t)c * N + j] * __expf(pm[(size_t)c * N + j] - m);
        m_col[mat * N + j] = m;
        isc[mat * N + j] = 1.0f / sqrtf(s);
    }
}

__global__ void init_small(double* acc, float* sp, float* sn)
{
    const int idx = blockIdx.x * 256 + threadIdx.x;
    if (idx == 0) *acc = 0.0;
    if (idx < N) { sp[idx] = 0.f; sn[idx] = 0.f; }
}

// ---------------------------------------------------------------------------
// pv via MFMA: A fp32 tile -> P (fp32 rowsums -> sp/sn), split P to bf16
// hi/lo in LDS, MFMA P @ B (B = RTN-bf16, transposed [d][j], hi only).
// ---------------------------------------------------------------------------
__global__ __launch_bounds__(256) void pv_mfma(
    const float* __restrict__ Apos, const float* __restrict__ Aneg,
    const u16* __restrict__ Yth, const u16* __restrict__ Xth,
    const float* __restrict__ m_row, const float* __restrict__ isr,
    const float* __restrict__ m_col, const float* __restrict__ isc,
    float* __restrict__ u_part, float* __restrict__ w_part,
    float* __restrict__ sp_arr, float* __restrict__ sn_arr)
{
    const int mat = blockIdx.z;
    const float* Am = mat ? Aneg : Apos;
    const u16* Bh = mat ? Xth : Yth;
    const float* mc = m_col + mat * N;
    const float* ic = isc + mat * N;
    float* Cp = (mat ? w_part : u_part) + (size_t)blockIdx.y * (N * D);
    float* spn = mat ? sn_arr : sp_arr;

    __shared__ u16 BhS[128][72];
    __shared__ u16 PhS[64][72], PlS[64][72];
    __shared__ float mrS[64], isrS[64];

    const int t = threadIdx.x;
    const int w = t >> 6, lane = t & 63;
    const int quad = lane >> 4, l16 = lane & 15;
    const int bm = blockIdx.x * 64;
    const int jbase = blockIdx.y * (N / KSPLIT);
    const int arow = t >> 4;          // 0..15
    const int aj = (t & 15) << 2;     // 0..60

    if (t < 64) { mrS[t] = m_row[bm + t]; isrS[t] = isr[bm + t]; }

    f32x4 acc[8] = {};
    float rs[4] = {0.f, 0.f, 0.f, 0.f};

    for (int jt = 0; jt < (N / KSPLIT) / 64; ++jt) {
        const int j0 = jbase + jt * 64;
        __syncthreads();   // protect previous iteration's LDS reads (+ mrS init)
        #pragma unroll
        for (int p = 0; p < 4; ++p) {
            int slot = t + p * 256;
            int d = slot >> 3, joff = (slot & 7) << 3;
            *(u16x8*)&BhS[d][joff] = *(const u16x8*)(Bh + (size_t)d * N + j0 + joff);
        }
        float4 mcv = *(const float4*)(mc + j0 + aj);
        float4 icv = *(const float4*)(ic + j0 + aj);
        #pragma unroll
        for (int s = 0; s < 4; ++s) {
            int row = arow + s * 16;
            float4 av = *(const float4*)(Am + (size_t)(bm + row) * N + j0 + aj);
            float mr = mrS[row], sr = isrS[row];
            float p0 = __expf(av.x - 0.5f * (mr + mcv.x)) * (sr * icv.x);
            float p1 = __expf(av.y - 0.5f * (mr + mcv.y)) * (sr * icv.y);
            float p2 = __expf(av.z - 0.5f * (mr + mcv.z)) * (sr * icv.z);
            float p3 = __expf(av.w - 0.5f * (mr + mcv.w)) * (sr * icv.w);
            rs[s] += p0 + p1 + p2 + p3;
            ushort4 hv, lv;
            split1(p0, hv.x, lv.x); split1(p1, hv.y, lv.y);
            split1(p2, hv.z, lv.z); split1(p3, hv.w, lv.w);
            *(ushort4*)&PhS[row][aj] = hv;
            *(ushort4*)&PlS[row][aj] = lv;
        }
        __syncthreads();
        #pragma unroll
        for (int ks = 0; ks < 2; ++ks) {
            const int kk = ks * 32 + quad * 8;
            bf16x8 ph = *(const bf16x8*)&PhS[w * 16 + l16][kk];
            bf16x8 pl = *(const bf16x8*)&PlS[w * 16 + l16][kk];
            #pragma unroll
            for (int ni = 0; ni < 8; ++ni) {
                bf16x8 bh = *(const bf16x8*)&BhS[ni * 16 + l16][kk];
                acc[ni] = MFMA(ph, bh, acc[ni]);
                acc[ni] = MFMA(pl, bh, acc[ni]);
            }
        }
    }
    #pragma unroll
    for (int ni = 0; ni < 8; ++ni)
        #pragma unroll
        for (int r = 0; r < 4; ++r) {
            int row = w * 16 + quad * 4 + r;
            int col = ni * 16 + l16;
            Cp[(size_t)(bm + row) * D + col] = acc[ni][r];
        }
    #pragma unroll
    for (int s = 0; s < 4; ++s) {
        float v = rs[s];
        v += __shfl_xor(v, 1); v += __shfl_xor(v, 2);
        v += __shfl_xor(v, 4); v += __shfl_xor(v, 8);
        if (l16 == 0) atomicAdd(&spn[bm + arow + s * 16], v);
    }
}

// ---------------------------------------------------------------------------
// Sum split-K partials, V = sn*u - sp*sn*w, accumulate sum(V^2).
// ---------------------------------------------------------------------------
__global__ __launch_bounds__(256) void final_reduce(const float* __restrict__ u_part,
    const float* __restrict__ w_part, const float* __restrict__ sp_arr,
    const float* __restrict__ sn_arr, double* __restrict__ acc_out)
{
    __shared__ float red[256];
    const int t = threadIdx.x;
    const int idx = blockIdx.x * 256 + t;
    float u = 0.f, w = 0.f;
    #pragma unroll
    for (int c = 0; c < KSPLIT; ++c) {
        u += u_part[(size_t)c * (N * D) + idx];
        w += w_part[(size_t)c * (N * D) + idx];
    }
    const int i = idx >> 7;
    const float sn = sn_arr[i];
    const float v = sn * u - sp_arr[i] * sn * w;
    red[t] = v * v; __syncthreads();
    for (int s = 128; s > 0; s >>= 1) { if (t < s) red[t] += red[t + s]; __syncthreads(); }
    if (!t) atomicAdd(acc_out, (double)red[0]);
}

__global__ void finalize(const double* __restrict__ acc, float* __restrict__ out)
{
    out[0] = (float)(*acc * (1.0 / ((double)N * (double)D)));
}

// ---------------------------------------------------------------------------
extern "C" void kernel_launch(void* const* d_in, const int* in_sizes, int n_in,
                              void* d_out, int out_size, void* d_ws, size_t ws_size,
                              hipStream_t stream)
{
    const float* y_pos = (const float*)d_in[0];
    const float* eps   = (const float*)d_in[1];
    const float* W_in  = (const float*)d_in[2];
    const float* b_in  = (const float*)d_in[3];
    const float* W_blk = (const float*)d_in[4];
    const float* b_blk = (const float*)d_in[5];
    const float* W_out = (const float*)d_in[6];
    const float* b_out = (const float*)d_in[7];
    float* out = (float*)d_out;
    (void)in_sizes; (void)n_in; (void)out_size; (void)ws_size;

    char* p = (char*)d_ws;
    auto alloc = [&](size_t bytes) {
        char* r = p;
        p += (bytes + 255) & ~(size_t)255;
        return r;
    };
    // --- small arrays ---
    double* acc  = (double*)alloc(8);
    float* sp     = (float*)alloc(N * 4);
    float* sn     = (float*)alloc(N * 4);
    float* m_row  = (float*)alloc(N * 4);
    float* isr    = (float*)alloc(N * 4);
    float* m_col  = (float*)alloc(2 * N * 4);
    float* isc    = (float*)alloc(2 * N * 4);
    float* nx     = (float*)alloc(N * 4);
    float* ny     = (float*)alloc(N * 4);
    // --- eh/el (2 MB; only live through the first gen layer) ---
    u16* eh = (u16*)alloc((size_t)N * D * 2);
    u16* el = (u16*)alloc((size_t)N * D * 2);
    // --- xo fp32 + bf16 x/y arrays ---
    float* xo  = (float*)alloc((size_t)N * D * 4);
    u16* xh    = (u16*)alloc((size_t)N * D * 2);
    u16* xl    = (u16*)alloc((size_t)N * D * 2);
    u16* xth   = (u16*)alloc((size_t)N * D * 2);
    u16* yh    = (u16*)alloc((size_t)N * D * 2);
    u16* yl    = (u16*)alloc((size_t)N * D * 2);
    u16* yth   = (u16*)alloc((size_t)N * D * 2);
    // --- generator region (21 MB): activations + weights; later aliased by
    //     stats partials (8 MB, dist->combine) then u/w_part (16 MB, pv->red)
    char* genreg = alloc((size_t)(4 * (size_t)N * H * 2
                                + 2 * (size_t)H * D * 2
                                + 2 * (size_t)4 * H * H * 2
                                + 2 * (size_t)D * H * 2));
    u16* x0h = (u16*)genreg;
    u16* x0l = x0h + (size_t)N * H;
    u16* x1h = x0l + (size_t)N * H;
    u16* x1l = x1h + (size_t)N * H;
    u16* wih = x1l + (size_t)N * H;
    u16* wil = wih + (size_t)H * D;
    u16* wbh = wil + (size_t)H * D;
    u16* wbl = wbh + (size_t)4 * H * H;
    u16* woh = wbl + (size_t)4 * H * H;
    u16* wol = woh + (size_t)D * H;
    // aliases (disjoint lifetimes, stream-ordered):
    float* prm_p = (float*)genreg;                 // 64*N each = 1 MB
    float* prs_p = prm_p + 64 * N;
    float* prm_n = prs_p + 64 * N;
    float* prs_n = prm_n + 64 * N;
    float* pcm_p = prs_n + 64 * N;
    float* pcs_p = pcm_p + 64 * N;
    float* pcm_n = pcs_p + 64 * N;
    float* pcs_n = pcm_n + 64 * N;                 // ends at 8 MB
    float* u_part = (float*)genreg;                // KSPLIT*N*D = 8 MB
    float* w_part = u_part + (size_t)KSPLIT * N * D;
    // --- the big ones (128 MB) ---
    float* Apos = (float*)alloc((size_t)N * N * 4);
    float* Aneg = (float*)alloc((size_t)N * N * 4);

    init_small<<<16, 256, 0, stream>>>(acc, sp, sn);

    // --- split inputs/weights to bf16 hi/lo ---
    SplitArgs sa;
    sa.d[0] = { eps,   eh,  el,  N * D };
    sa.d[1] = { y_pos, yh,  yl,  N * D };
    sa.d[2] = { W_in,  wih, wil, H * D };
    sa.d[3] = { W_blk, wbh, wbl, 4 * H * H };
    sa.d[4] = { W_out, woh, wol, D * H };
    split_multi<<<dim3(1024, 5), 256, 0, stream>>>(sa);

    // --- generator (MFMA split-bf16) ---
    dim3 gh(H / 64, N / 128);
    gen_gemm<<<gh, 128, 0, stream>>>(eh, el, wih, wil, b_in,
                                     nullptr, x0h, x0l, N, H, D, 0);
    gen_gemm<<<gh, 128, 0, stream>>>(x0h, x0l, wbh + 0 * H * H, wbl + 0 * H * H,
                                     b_blk + 0 * H, nullptr, x1h, x1l, N, H, H, 1);
    gen_gemm<<<gh, 128, 0, stream>>>(x1h, x1l, wbh + 1 * H * H, wbl + 1 * H * H,
                                     b_blk + 1 * H, nullptr, x0h, x0l, N, H, H, 1);
    gen_gemm<<<gh, 128, 0, stream>>>(x0h, x0l, wbh + 2 * H * H, wbl + 2 * H * H,
                                     b_blk + 2 * H, nullptr, x1h, x1l, N, H, H, 1);
    gen_gemm<<<gh, 128, 0, stream>>>(x1h, x1l, wbh + 3 * H * H, wbl + 3 * H * H,
                                     b_blk + 3 * H, nullptr, x0h, x0l, N, H, H, 1);
    gen_gemm<<<dim3(D / 64, N / 128), 128, 0, stream>>>(x0h, x0l, woh, wol, b_out,
                                     xo, xh, xl, N, D, H, 0);

    // --- norms + RTN transposes ---
    row_norms<<<dim3(N, 2), 128, 0, stream>>>(xo, y_pos, nx, ny);
    transpose_rtn<<<dim3(N / 32, D / 32, 2), 256, 0, stream>>>(xo, y_pos, xth, yth);

    // --- distance matrices + fused softmax partial stats ---
    dim3 gd(N / 128, N / 128);
    dist_fused<<<gd, 256, 0, stream>>>(xh, xl, yh, yl, nx, ny, Apos,
                                       prm_p, prs_p, pcm_p, pcs_p, 0);
    dist_fused<<<gd, 256, 0, stream>>>(xh, xl, xh, xl, nx, nx, Aneg,
                                       prm_n, prs_n, pcm_n, pcs_n, 1);

    // --- combine partials into m_row/isr, m_col/isc ---
    stats_combine<<<48, 256, 0, stream>>>(prm_p, prs_p, prm_n, prs_n,
                                          pcm_p, pcs_p, pcm_n, pcs_n,
                                          m_row, isr, m_col, isc);

    // --- P@V via MFMA (P built on the fly; sp/sn fp32 via atomics) ---
    pv_mfma<<<dim3(N / 64, KSPLIT, 2), 256, 0, stream>>>(Apos, Aneg,
        yth, xth, m_row, isr, m_col, isc, u_part, w_part, sp, sn);

    // --- combine partials, V^2 reduction ---
    final_reduce<<<(N * D) / 256, 256, 0, stream>>>(u_part, w_part, sp, sn, acc);
    finalize<<<1, 1, 0, stream>>>(acc, out);
}

// Round 6
// 362.452 us; speedup vs baseline: 3.5830x; 1.2104x over previous
//
#include <hip/hip_runtime.h>
#include <math.h>

#define N 4096
#define D 128
#define H 512
#define INV_T 5.0f
#define KSPLIT 4

typedef short bf16x8 __attribute__((ext_vector_type(8)));
typedef float f32x4 __attribute__((ext_vector_type(4)));
typedef unsigned short u16x8 __attribute__((ext_vector_type(8)));
typedef unsigned short u16;

#define MFMA(a, b, c) __builtin_amdgcn_mfma_f32_16x16x32_bf16((a), (b), (c), 0, 0, 0)

// Split fp32 into hi/lo bf16 (truncation; residual truncated to bf16).
__device__ __forceinline__ void split1(float v, u16& h, u16& l)
{
    unsigned bv = __float_as_uint(v);
    unsigned hb = bv & 0xFFFF0000u;
    float r = v - __uint_as_float(hb);
    h = (u16)(hb >> 16);
    l = (u16)(__float_as_uint(r) >> 16);
}

__device__ __forceinline__ float bf2f(u16 h)
{
    return __uint_as_float(((unsigned)h) << 16);
}

// Round-to-nearest bf16 (unbiased — used for pv's B operand).
__device__ __forceinline__ u16 rtn_bf16(float v)
{
    unsigned u = __float_as_uint(v);
    return (u16)((u + 0x7FFFu + ((u >> 16) & 1u)) >> 16);
}

// ---------------------------------------------------------------------------
// One-shot splitter for up to 5 flat fp32 arrays -> bf16 hi/lo.
// ---------------------------------------------------------------------------
struct SplitDesc { const float* src; u16* h; u16* l; int n; };
struct SplitArgs { SplitDesc d[5]; };

__global__ __launch_bounds__(256) void split_multi(SplitArgs args)
{
    SplitDesc de = args.d[blockIdx.y];
    int idx = (blockIdx.x * 256 + threadIdx.x) * 4;
    if (idx >= de.n) return;
    float4 v = *(const float4*)(de.src + idx);
    ushort4 hv, lv;
    split1(v.x, hv.x, lv.x); split1(v.y, hv.y, lv.y);
    split1(v.z, hv.z, lv.z); split1(v.w, hv.w, lv.w);
    *(ushort4*)(de.h + idx) = hv;
    *(ushort4*)(de.l + idx) = lv;
}

// ---------------------------------------------------------------------------
// Transpose + RTN-bf16 + fused row-norm partials (atomicAdd into nx/ny).
// fp32 [4096][128] -> bf16 [128][4096]. z: 0=X, 1=Y. 32x32 tile, 256 thr.
// ---------------------------------------------------------------------------
__global__ __launch_bounds__(256) void transpose_rtn(
    const float* __restrict__ X, const float* __restrict__ Y,
    u16* __restrict__ Xth, u16* __restrict__ Yth,
    float* __restrict__ nx, float* __restrict__ ny)
{
    const float* src = blockIdx.z ? Y : X;
    u16* th = blockIdx.z ? Yth : Xth;
    float* nrm = blockIdx.z ? ny : nx;
    __shared__ float tile[32][33];
    const int t = threadIdx.x;
    const int r0 = blockIdx.x * 32, c0 = blockIdx.y * 32;
    {
        int rit = t >> 3, coff = (t & 7) * 4;
        float4 v = *(const float4*)(src + (size_t)(r0 + rit) * D + c0 + coff);
        tile[rit][coff + 0] = v.x; tile[rit][coff + 1] = v.y;
        tile[rit][coff + 2] = v.z; tile[rit][coff + 3] = v.w;
        // fused row-norm partial: 8 threads per row
        float sq = v.x * v.x + v.y * v.y + v.z * v.z + v.w * v.w;
        sq += __shfl_xor(sq, 1);
        sq += __shfl_xor(sq, 2);
        sq += __shfl_xor(sq, 4);
        if ((t & 7) == 0) atomicAdd(&nrm[r0 + rit], sq);
    }
    __syncthreads();
    {
        int cit = t >> 3, roff = (t & 7) * 4;
        ushort4 hv;
        hv.x = rtn_bf16(tile[roff + 0][cit]);
        hv.y = rtn_bf16(tile[roff + 1][cit]);
        hv.z = rtn_bf16(tile[roff + 2][cit]);
        hv.w = rtn_bf16(tile[roff + 3][cit]);
        *(ushort4*)(th + (size_t)(c0 + cit) * N + r0 + roff) = hv;
    }
}

// ---------------------------------------------------------------------------
// Generator GEMM via split-bf16 MFMA. C = A(MxK) @ B(NnxK)^T + bias,
// resid: C = (Ah+Al) + relu(...). Tile 128(M)x64(N), BK=32, 256 threads
// (4 waves, each 32 rows x 64 cols).
// ---------------------------------------------------------------------------
__global__ __launch_bounds__(256) void gen_gemm(
    const u16* __restrict__ Ah, const u16* __restrict__ Al,
    const u16* __restrict__ Bh, const u16* __restrict__ Bl,
    const float* __restrict__ bias,
    float* __restrict__ C, u16* __restrict__ Ch, u16* __restrict__ Cl,
    int M, int Nn, int K, int resid)
{
    __shared__ u16 AhS[128][40], AlS[128][40];
    __shared__ u16 BhS[64][40], BlS[64][40];
    const int t = threadIdx.x;
    const int w = t >> 6, lane = t & 63;
    const int quad = lane >> 4, l16 = lane & 15;
    const int bm = blockIdx.y * 128, bn = blockIdx.x * 64;
    f32x4 acc[2][4] = {};

    for (int k0 = 0; k0 < K; k0 += 32) {
        __syncthreads();
        #pragma unroll
        for (int p = 0; p < 2; ++p) {
            int slot = t + p * 256;
            int row = slot >> 2, koff = (slot & 3) << 3;
            size_t g = (size_t)(bm + row) * K + k0 + koff;
            *(u16x8*)&AhS[row][koff] = *(const u16x8*)(Ah + g);
            *(u16x8*)&AlS[row][koff] = *(const u16x8*)(Al + g);
        }
        {
            int row = t >> 2, koff = (t & 3) << 3;
            size_t g = (size_t)(bn + row) * K + k0 + koff;
            *(u16x8*)&BhS[row][koff] = *(const u16x8*)(Bh + g);
            *(u16x8*)&BlS[row][koff] = *(const u16x8*)(Bl + g);
        }
        __syncthreads();
        bf16x8 af[2], alf[2], bhf[4], blf[4];
        #pragma unroll
        for (int mi = 0; mi < 2; ++mi) {
            int r = w * 32 + mi * 16 + l16;
            af[mi]  = *(const bf16x8*)&AhS[r][quad * 8];
            alf[mi] = *(const bf16x8*)&AlS[r][quad * 8];
        }
        #pragma unroll
        for (int ni = 0; ni < 4; ++ni) {
            int r = ni * 16 + l16;
            bhf[ni] = *(const bf16x8*)&BhS[r][quad * 8];
            blf[ni] = *(const bf16x8*)&BlS[r][quad * 8];
        }
        #pragma unroll
        for (int mi = 0; mi < 2; ++mi)
            #pragma unroll
            for (int ni = 0; ni < 4; ++ni) {
                acc[mi][ni] = MFMA(af[mi], bhf[ni], acc[mi][ni]);
                acc[mi][ni] = MFMA(af[mi], blf[ni], acc[mi][ni]);
                acc[mi][ni] = MFMA(alf[mi], bhf[ni], acc[mi][ni]);
            }
    }
    #pragma unroll
    for (int mi = 0; mi < 2; ++mi)
        #pragma unroll
        for (int ni = 0; ni < 4; ++ni)
            #pragma unroll
            for (int r = 0; r < 4; ++r) {
                int gm = bm + w * 32 + mi * 16 + quad * 4 + r;
                int gn = bn + ni * 16 + l16;
                float v = acc[mi][ni][r] + bias[gn];
                if (resid) {
                    size_t o2 = (size_t)gm * K + gn;   // K==Nn for resid layers
                    float prev = bf2f(Ah[o2]) + bf2f(Al[o2]);
                    v = prev + fmaxf(v, 0.0f);
                }
                size_t o = (size_t)gm * Nn + gn;
                if (C) C[o] = v;
                u16 hh, ll; split1(v, hh, ll);
                Ch[o] = hh; Cl[o] = ll;
            }
}

// ---------------------------------------------------------------------------
// Distance via split-bf16 MFMA, fused softmax partial stats, pos+neg merged
// (blockIdx.z). Out = -INV_T*sqrt(max(na+nb-2*X@B^T,0)); diag(neg) -> -5e6.
// Row partials always; col partials only for pos (neg is symmetric: its col
// stats == its row stats).
// ---------------------------------------------------------------------------
__global__ __launch_bounds__(256) void dist_fused(
    const u16* __restrict__ Xh, const u16* __restrict__ Xl,
    const u16* __restrict__ Yh, const u16* __restrict__ Yl,
    const float* __restrict__ nx, const float* __restrict__ ny,
    float* __restrict__ Apos, float* __restrict__ Aneg,
    float* __restrict__ prm_p, float* __restrict__ prs_p,
    float* __restrict__ pcm_p, float* __restrict__ pcs_p,
    float* __restrict__ prm_n, float* __restrict__ prs_n)
{
    const int mat = blockIdx.z;                // 0: X vs Y ; 1: X vs X
    const u16* Bhp = mat ? Xh : Yh;
    const u16* Blp = mat ? Xl : Yl;
    const float* nb = mat ? nx : ny;
    float* Out = mat ? Aneg : Apos;
    float* prm = mat ? prm_n : prm_p;
    float* prs = mat ? prs_n : prs_p;

    __shared__ u16 XhS[128][40], XlS[128][40], YhS[128][40], YlS[128][40];
    const int t = threadIdx.x;
    const int w = t >> 6, lane = t & 63;
    const int quad = lane >> 4, l16 = lane & 15;
    const int wm = w & 1, wn = w >> 1;
    const int bm = blockIdx.y * 128, bn = blockIdx.x * 128;
    f32x4 acc[4][4] = {};

    for (int k0 = 0; k0 < D; k0 += 32) {
        __syncthreads();
        #pragma unroll
        for (int p = 0; p < 2; ++p) {
            int slot = t + p * 256;
            int row = slot >> 2, koff = (slot & 3) << 3;
            size_t gx = (size_t)(bm + row) * D + k0 + koff;
            size_t gy = (size_t)(bn + row) * D + k0 + koff;
            *(u16x8*)&XhS[row][koff] = *(const u16x8*)(Xh + gx);
            *(u16x8*)&XlS[row][koff] = *(const u16x8*)(Xl + gx);
            *(u16x8*)&YhS[row][koff] = *(const u16x8*)(Bhp + gy);
            *(u16x8*)&YlS[row][koff] = *(const u16x8*)(Blp + gy);
        }
        __syncthreads();
        bf16x8 af[4], alf[4], bhf[4], blf[4];
        #pragma unroll
        for (int mi = 0; mi < 4; ++mi) {
            int r = wm * 64 + mi * 16 + l16;
            af[mi]  = *(const bf16x8*)&XhS[r][quad * 8];
            alf[mi] = *(const bf16x8*)&XlS[r][quad * 8];
        }
        #pragma unroll
        for (int ni = 0; ni < 4; ++ni) {
            int r = wn * 64 + ni * 16 + l16;
            bhf[ni] = *(const bf16x8*)&YhS[r][quad * 8];
            blf[ni] = *(const bf16x8*)&YlS[r][quad * 8];
        }
        #pragma unroll
        for (int mi = 0; mi < 4; ++mi)
            #pragma unroll
            for (int ni = 0; ni < 4; ++ni) {
                acc[mi][ni] = MFMA(af[mi], bhf[ni], acc[mi][ni]);
                acc[mi][ni] = MFMA(af[mi], blf[ni], acc[mi][ni]);
                acc[mi][ni] = MFMA(alf[mi], bhf[ni], acc[mi][ni]);
            }
    }
    // --- transform in place: acc -> a = -5*sqrt(d2); write A ---
    #pragma unroll
    for (int mi = 0; mi < 4; ++mi)
        #pragma unroll
        for (int r = 0; r < 4; ++r) {
            int gm = bm + wm * 64 + mi * 16 + quad * 4 + r;
            float nxm = nx[gm];
            #pragma unroll
            for (int ni = 0; ni < 4; ++ni) {
                int gn = bn + wn * 64 + ni * 16 + l16;
                float d2 = nxm + nb[gn] - 2.0f * acc[mi][ni][r];
                float a = -sqrtf(fmaxf(d2, 0.0f)) * INV_T;
                if (mat && gm == gn) a = -5.0e6f;
                acc[mi][ni][r] = a;
                Out[(size_t)gm * N + gn] = a;
            }
        }
    // --- row partials: per (mi,r), reduce over ni (in-lane) + l16 (shfl) ---
    const int ct = blockIdx.x * 2 + wn;
    #pragma unroll
    for (int mi = 0; mi < 4; ++mi)
        #pragma unroll
        for (int r = 0; r < 4; ++r) {
            float m = fmaxf(fmaxf(acc[mi][0][r], acc[mi][1][r]),
                            fmaxf(acc[mi][2][r], acc[mi][3][r]));
            m = fmaxf(m, __shfl_xor(m, 1));
            m = fmaxf(m, __shfl_xor(m, 2));
            m = fmaxf(m, __shfl_xor(m, 4));
            m = fmaxf(m, __shfl_xor(m, 8));
            float s = __expf(acc[mi][0][r] - m) + __expf(acc[mi][1][r] - m)
                    + __expf(acc[mi][2][r] - m) + __expf(acc[mi][3][r] - m);
            s += __shfl_xor(s, 1); s += __shfl_xor(s, 2);
            s += __shfl_xor(s, 4); s += __shfl_xor(s, 8);
            if (l16 == 0) {
                int grow = bm + wm * 64 + mi * 16 + quad * 4 + r;
                prm[(size_t)ct * N + grow] = m;
                prs[(size_t)ct * N + grow] = s;
            }
        }
    // --- col partials (pos only): per ni, in-lane over (mi,r) + quad shfl ---
    if (mat == 0) {
        const int rt = blockIdx.y * 2 + wm;
        #pragma unroll
        for (int ni = 0; ni < 4; ++ni) {
            float m = -3.0e38f;
            #pragma unroll
            for (int mi = 0; mi < 4; ++mi)
                #pragma unroll
                for (int r = 0; r < 4; ++r)
                    m = fmaxf(m, acc[mi][ni][r]);
            m = fmaxf(m, __shfl_xor(m, 16));
            m = fmaxf(m, __shfl_xor(m, 32));
            float s = 0.f;
            #pragma unroll
            for (int mi = 0; mi < 4; ++mi)
                #pragma unroll
                for (int r = 0; r < 4; ++r)
                    s += __expf(acc[mi][ni][r] - m);
            s += __shfl_xor(s, 16);
            s += __shfl_xor(s, 32);
            if (quad == 0) {
                int gcol = bn + wn * 64 + ni * 16 + l16;
                pcm_p[(size_t)rt * N + gcol] = m;
                pcs_p[(size_t)rt * N + gcol] = s;
            }
        }
    }
}

// ---------------------------------------------------------------------------
// Combine partials: idx<N -> row stats (pos+neg, 128 partials);
// idx<2N -> pos col stats (64 partials); idx<3N -> neg col stats (= neg row
// partials, by symmetry of dist(x,x)).
// ---------------------------------------------------------------------------
__global__ __launch_bounds__(256) void stats_combine(
    const float* __restrict__ prm_p, const float* __restrict__ prs_p,
    const float* __restrict__ prm_n, const float* __restrict__ prs_n,
    const float* __restrict__ pcm_p, const float* __restrict__ pcs_p,
    float* __restrict__ m_row, float* __restrict__ isr,
    float* __restrict__ m_col, float* __restrict__ isc)
{
    const int idx = blockIdx.x * 256 + threadIdx.x;
    if (idx < N) {
        const int i = idx;
        float m = -3.0e38f;
        for (int c = 0; c < 64; ++c) {
            m = fmaxf(m, prm_p[(size_t)c * N + i]);
            m = fmaxf(m, prm_n[(size_t)c * N + i]);
        }
        float s = 0.f;
        for (int c = 0; c < 64; ++c) {
            s += prs_p[(size_t)c * N + i] * __expf(prm_p[(size_t)c * N + i] - m);
            s += prs_n[(size_t)c * N + i] * __expf(prm_n[(size_t)c * N + i] - m);
        }
        m_row[i] = m;
        isr[i] = 1.0f / sqrtf(s);
    } else {
        const int mat = (idx - N) >> 12;
        const int j = idx & (N - 1);
        const float* pm = mat ? prm_n : pcm_p;
        const float* ps = mat ? prs_n : pcs_p;
        float m = -3.0e38f;
        for (int c = 0; c < 64; ++c)
            m = fmaxf(m, pm[(size_t)c * N + j]);
        float s = 0.f;
        for (int c = 0; c < 64; ++c)
            s += ps[(size_t)c * N + j] * __expf(pm[(size_t)c * N + j] - m);
        m_col[mat * N + j] = m;
        isc[mat * N + j] = 1.0f / sqrtf(s);
    }
}

__global__ void init_small(double* acc, float* sp, float* sn, float* nx, float* ny)
{
    const int idx = blockIdx.x * 256 + threadIdx.x;
    if (idx == 0) *acc = 0.0;
    if (idx < N) { sp[idx] = 0.f; sn[idx] = 0.f; nx[idx] = 0.f; ny[idx] = 0.f; }
}

// ---------------------------------------------------------------------------
// pv via MFMA: A fp32 tile -> P (fp32 rowsums -> sp/sn), split P to bf16
// hi/lo in LDS, MFMA P @ B (B = RTN-bf16, transposed [d][j], hi only).
// ---------------------------------------------------------------------------
__global__ __launch_bounds__(256) void pv_mfma(
    const float* __restrict__ Apos, const float* __restrict__ Aneg,
    const u16* __restrict__ Yth, const u16* __restrict__ Xth,
    const float* __restrict__ m_row, const float* __restrict__ isr,
    const float* __restrict__ m_col, const float* __restrict__ isc,
    float* __restrict__ u_part, float* __restrict__ w_part,
    float* __restrict__ sp_arr, float* __restrict__ sn_arr)
{
    const int mat = blockIdx.z;
    const float* Am = mat ? Aneg : Apos;
    const u16* Bh = mat ? Xth : Yth;
    const float* mc = m_col + mat * N;
    const float* ic = isc + mat * N;
    float* Cp = (mat ? w_part : u_part) + (size_t)blockIdx.y * (N * D);
    float* spn = mat ? sn_arr : sp_arr;

    __shared__ u16 BhS[128][72];
    __shared__ u16 PhS[64][72], PlS[64][72];
    __shared__ float mrS[64], isrS[64];

    const int t = threadIdx.x;
    const int w = t >> 6, lane = t & 63;
    const int quad = lane >> 4, l16 = lane & 15;
    const int bm = blockIdx.x * 64;
    const int jbase = blockIdx.y * (N / KSPLIT);
    const int arow = t >> 4;          // 0..15
    const int aj = (t & 15) << 2;     // 0..60

    if (t < 64) { mrS[t] = m_row[bm + t]; isrS[t] = isr[bm + t]; }

    f32x4 acc[8] = {};
    float rs[4] = {0.f, 0.f, 0.f, 0.f};

    for (int jt = 0; jt < (N / KSPLIT) / 64; ++jt) {
        const int j0 = jbase + jt * 64;
        __syncthreads();   // protect previous iteration's LDS reads (+ mrS init)
        #pragma unroll
        for (int p = 0; p < 4; ++p) {
            int slot = t + p * 256;
            int d = slot >> 3, joff = (slot & 7) << 3;
            *(u16x8*)&BhS[d][joff] = *(const u16x8*)(Bh + (size_t)d * N + j0 + joff);
        }
        float4 mcv = *(const float4*)(mc + j0 + aj);
        float4 icv = *(const float4*)(ic + j0 + aj);
        #pragma unroll
        for (int s = 0; s < 4; ++s) {
            int row = arow + s * 16;
            float4 av = *(const float4*)(Am + (size_t)(bm + row) * N + j0 + aj);
            float mr = mrS[row], sr = isrS[row];
            float p0 = __expf(av.x - 0.5f * (mr + mcv.x)) * (sr * icv.x);
            float p1 = __expf(av.y - 0.5f * (mr + mcv.y)) * (sr * icv.y);
            float p2 = __expf(av.z - 0.5f * (mr + mcv.z)) * (sr * icv.z);
            float p3 = __expf(av.w - 0.5f * (mr + mcv.w)) * (sr * icv.w);
            rs[s] += p0 + p1 + p2 + p3;
            ushort4 hv, lv;
            split1(p0, hv.x, lv.x); split1(p1, hv.y, lv.y);
            split1(p2, hv.z, lv.z); split1(p3, hv.w, lv.w);
            *(ushort4*)&PhS[row][aj] = hv;
            *(ushort4*)&PlS[row][aj] = lv;
        }
        __syncthreads();
        #pragma unroll
        for (int ks = 0; ks < 2; ++ks) {
            const int kk = ks * 32 + quad * 8;
            bf16x8 ph = *(const bf16x8*)&PhS[w * 16 + l16][kk];
            bf16x8 pl = *(const bf16x8*)&PlS[w * 16 + l16][kk];
            #pragma unroll
            for (int ni = 0; ni < 8; ++ni) {
                bf16x8 bh = *(const bf16x8*)&BhS[ni * 16 + l16][kk];
                acc[ni] = MFMA(ph, bh, acc[ni]);
                acc[ni] = MFMA(pl, bh, acc[ni]);
            }
        }
    }
    #pragma unroll
    for (int ni = 0; ni < 8; ++ni)
        #pragma unroll
        for (int r = 0; r < 4; ++r) {
            int row = w * 16 + quad * 4 + r;
            int col = ni * 16 + l16;
            Cp[(size_t)(bm + row) * D + col] = acc[ni][r];
        }
    #pragma unroll
    for (int s = 0; s < 4; ++s) {
        float v = rs[s];
        v += __shfl_xor(v, 1); v += __shfl_xor(v, 2);
        v += __shfl_xor(v, 4); v += __shfl_xor(v, 8);
        if (l16 == 0) atomicAdd(&spn[bm + arow + s * 16], v);
    }
}

// ---------------------------------------------------------------------------
// Sum split-K partials, V = sn*u - sp*sn*w, accumulate sum(V^2).
// ---------------------------------------------------------------------------
__global__ __launch_bounds__(256) void final_reduce(const float* __restrict__ u_part,
    const float* __restrict__ w_part, const float* __restrict__ sp_arr,
    const float* __restrict__ sn_arr, double* __restrict__ acc_out)
{
    __shared__ float red[256];
    const int t = threadIdx.x;
    const int idx = blockIdx.x * 256 + t;
    float u = 0.f, w = 0.f;
    #pragma unroll
    for (int c = 0; c < KSPLIT; ++c) {
        u += u_part[(size_t)c * (N * D) + idx];
        w += w_part[(size_t)c * (N * D) + idx];
    }
    const int i = idx >> 7;
    const float sn = sn_arr[i];
    const float v = sn * u - sp_arr[i] * sn * w;
    red[t] = v * v; __syncthreads();
    for (int s = 128; s > 0; s >>= 1) { if (t < s) red[t] += red[t + s]; __syncthreads(); }
    if (!t) atomicAdd(acc_out, (double)red[0]);
}

__global__ void finalize(const double* __restrict__ acc, float* __restrict__ out)
{
    out[0] = (float)(*acc * (1.0 / ((double)N * (double)D)));
}

// ---------------------------------------------------------------------------
extern "C" void kernel_launch(void* const* d_in, const int* in_sizes, int n_in,
                              void* d_out, int out_size, void* d_ws, size_t ws_size,
                              hipStream_t stream)
{
    const float* y_pos = (const float*)d_in[0];
    const float* eps   = (const float*)d_in[1];
    const float* W_in  = (const float*)d_in[2];
    const float* b_in  = (const float*)d_in[3];
    const float* W_blk = (const float*)d_in[4];
    const float* b_blk = (const float*)d_in[5];
    const float* W_out = (const float*)d_in[6];
    const float* b_out = (const float*)d_in[7];
    float* out = (float*)d_out;
    (void)in_sizes; (void)n_in; (void)out_size; (void)ws_size;

    char* p = (char*)d_ws;
    auto alloc = [&](size_t bytes) {
        char* r = p;
        p += (bytes + 255) & ~(size_t)255;
        return r;
    };
    // --- small arrays ---
    double* acc  = (double*)alloc(8);
    float* sp     = (float*)alloc(N * 4);
    float* sn     = (float*)alloc(N * 4);
    float* m_row  = (float*)alloc(N * 4);
    float* isr    = (float*)alloc(N * 4);
    float* m_col  = (float*)alloc(2 * N * 4);
    float* isc    = (float*)alloc(2 * N * 4);
    float* nx     = (float*)alloc(N * 4);
    float* ny     = (float*)alloc(N * 4);
    // --- eh/el (2 MB; only live through the first gen layer) ---
    u16* eh = (u16*)alloc((size_t)N * D * 2);
    u16* el = (u16*)alloc((size_t)N * D * 2);
    // --- xo fp32 + bf16 x/y arrays ---
    float* xo  = (float*)alloc((size_t)N * D * 4);
    u16* xh    = (u16*)alloc((size_t)N * D * 2);
    u16* xl    = (u16*)alloc((size_t)N * D * 2);
    u16* xth   = (u16*)alloc((size_t)N * D * 2);
    u16* yh    = (u16*)alloc((size_t)N * D * 2);
    u16* yl    = (u16*)alloc((size_t)N * D * 2);
    u16* yth   = (u16*)alloc((size_t)N * D * 2);
    // --- generator region (21 MB): activations + weights; later aliased by
    //     stats partials (7 MB, dist->combine) then u/w_part (16 MB, pv->red)
    char* genreg = alloc((size_t)(4 * (size_t)N * H * 2
                                + 2 * (size_t)H * D * 2
                                + 2 * (size_t)4 * H * H * 2
                                + 2 * (size_t)D * H * 2));
    u16* x0h = (u16*)genreg;
    u16* x0l = x0h + (size_t)N * H;
    u16* x1h = x0l + (size_t)N * H;
    u16* x1l = x1h + (size_t)N * H;
    u16* wih = x1l + (size_t)N * H;
    u16* wil = wih + (size_t)H * D;
    u16* wbh = wil + (size_t)H * D;
    u16* wbl = wbh + (size_t)4 * H * H;
    u16* woh = wbl + (size_t)4 * H * H;
    u16* wol = woh + (size_t)D * H;
    // aliases (disjoint lifetimes, stream-ordered):
    float* prm_p = (float*)genreg;                 // 64*N each = 1 MB
    float* prs_p = prm_p + 64 * N;
    float* prm_n = prs_p + 64 * N;
    float* prs_n = prm_n + 64 * N;
    float* pcm_p = prs_n + 64 * N;
    float* pcs_p = pcm_p + 64 * N;                 // ends at 6 MB
    float* u_part = (float*)genreg;                // KSPLIT*N*D = 8 MB
    float* w_part = u_part + (size_t)KSPLIT * N * D;
    // --- the big ones (128 MB) ---
    float* Apos = (float*)alloc((size_t)N * N * 4);
    float* Aneg = (float*)alloc((size_t)N * N * 4);

    init_small<<<16, 256, 0, stream>>>(acc, sp, sn, nx, ny);

    // --- split inputs/weights to bf16 hi/lo ---
    SplitArgs sa;
    sa.d[0] = { eps,   eh,  el,  N * D };
    sa.d[1] = { y_pos, yh,  yl,  N * D };
    sa.d[2] = { W_in,  wih, wil, H * D };
    sa.d[3] = { W_blk, wbh, wbl, 4 * H * H };
    sa.d[4] = { W_out, woh, wol, D * H };
    split_multi<<<dim3(1024, 5), 256, 0, stream>>>(sa);

    // --- generator (MFMA split-bf16) ---
    dim3 gh(H / 64, N / 128);
    gen_gemm<<<gh, 256, 0, stream>>>(eh, el, wih, wil, b_in,
                                     nullptr, x0h, x0l, N, H, D, 0);
    gen_gemm<<<gh, 256, 0, stream>>>(x0h, x0l, wbh + 0 * H * H, wbl + 0 * H * H,
                                     b_blk + 0 * H, nullptr, x1h, x1l, N, H, H, 1);
    gen_gemm<<<gh, 256, 0, stream>>>(x1h, x1l, wbh + 1 * H * H, wbl + 1 * H * H,
                                     b_blk + 1 * H, nullptr, x0h, x0l, N, H, H, 1);
    gen_gemm<<<gh, 256, 0, stream>>>(x0h, x0l, wbh + 2 * H * H, wbl + 2 * H * H,
                                     b_blk + 2 * H, nullptr, x1h, x1l, N, H, H, 1);
    gen_gemm<<<gh, 256, 0, stream>>>(x1h, x1l, wbh + 3 * H * H, wbl + 3 * H * H,
                                     b_blk + 3 * H, nullptr, x0h, x0l, N, H, H, 1);
    gen_gemm<<<dim3(D / 64, N / 128), 256, 0, stream>>>(x0h, x0l, woh, wol, b_out,
                                     xo, xh, xl, N, D, H, 0);

    // --- RTN transposes + fused row norms ---
    transpose_rtn<<<dim3(N / 32, D / 32, 2), 256, 0, stream>>>(
        xo, y_pos, xth, yth, nx, ny);

    // --- distance matrices + fused softmax partial stats (pos+neg merged) ---
    dist_fused<<<dim3(N / 128, N / 128, 2), 256, 0, stream>>>(
        xh, xl, yh, yl, nx, ny, Apos, Aneg,
        prm_p, prs_p, pcm_p, pcs_p, prm_n, prs_n);

    // --- combine partials into m_row/isr, m_col/isc ---
    stats_combine<<<48, 256, 0, stream>>>(prm_p, prs_p, prm_n, prs_n,
                                          pcm_p, pcs_p,
                                          m_row, isr, m_col, isc);

    // --- P@V via MFMA (P built on the fly; sp/sn fp32 via atomics) ---
    pv_mfma<<<dim3(N / 64, KSPLIT, 2), 256, 0, stream>>>(Apos, Aneg,
        yth, xth, m_row, isr, m_col, isc, u_part, w_part, sp, sn);

    // --- combine partials, V^2 reduction ---
    final_reduce<<<(N * D) / 256, 256, 0, stream>>>(u_part, w_part, sp, sn, acc);
    finalize<<<1, 1, 0, stream>>>(acc, out);
}